// Round 10
// baseline (403.866 us; speedup 1.0000x reference)
//
#include <hip/hip_runtime.h>
#include <hip/hip_cooperative_groups.h>
#include <math.h>

namespace cg = cooperative_groups;

// Problem constants
#define B_    1024
#define D_    768
#define C_    150
#define P_    64
#define TWOD  1536
#define NCLS  151   // C+1
#define CPAD  256   // partial row: 0..150 logits, 151..191 junk, 192..255 u

// fused phase: 128b x 64c per job, 8x4/thr, e split 16 ways (R8-proven)
#define ECHUNKS 16
#define ECHUNK  96

#define ASTR  40    // gemm LDS stride (bf16)
#define USTRU 120   // u-path LDS stride (halves)
#define USTR  72    // pair LDS stride (halves)

// Workspace layout (float offsets)
#define OFF_MH      0
#define OFF_XH      (OFF_MH + (C_ * TWOD) / 2)
#define OFF_PARTIAL (OFF_XH + (B_ * TWOD) / 2)
#define OFF_UHF     (OFF_PARTIAL + ECHUNKS * B_ * CPAD)
#define OFF_SQN     (OFF_UHF + (B_ * P_) / 2)
#define OFF_CLS     (OFF_SQN + B_)
#define OFF_PAIR    (OFF_CLS + B_)
#define OFF_XBF     (OFF_PAIR + 1024)
#define OFF_MEMBF   (OFF_XBF + (B_ * D_) / 2)
#define OFF_WBF     (OFF_MEMBF + (C_ * D_) / 2)
#define OFF_P2H     (OFF_WBF + (TWOD * TWOD) / 2)
#define OFF_P1H     (OFF_P2H + (P_ * TWOD) / 2)
// end ~6.82M floats ~ 27.3 MB

typedef __bf16    bfx8   __attribute__((ext_vector_type(8)));
typedef _Float16  fp16x8 __attribute__((ext_vector_type(8)));
typedef _Float16  h2v    __attribute__((ext_vector_type(2)));
typedef float     f32x4  __attribute__((ext_vector_type(4)));

__device__ inline ushort f2bf(float f) {
    union { float f; unsigned u; } c; c.f = f;
    unsigned r = c.u + 0x7fffu + ((c.u >> 16) & 1u);
    return (ushort)(r >> 16);
}
__device__ inline ushort f2h(float f) {
    _Float16 h = (_Float16)f;
    return __builtin_bit_cast(ushort, h);
}
__device__ inline unsigned addrelu2(unsigned a, unsigned m) {
    h2v s = __builtin_bit_cast(h2v, a) + __builtin_bit_cast(h2v, m);
    h2v z = {(_Float16)0.f, (_Float16)0.f};
    s = __builtin_elementwise_max(s, z);
    return __builtin_bit_cast(unsigned, s);
}
__device__ inline unsigned relu2(unsigned a) {
    h2v s = __builtin_bit_cast(h2v, a);
    h2v z = {(_Float16)0.f, (_Float16)0.f};
    s = __builtin_elementwise_max(s, z);
    return __builtin_bit_cast(unsigned, s);
}
__device__ inline float dot2acc(unsigned a, unsigned b, float c) {
    return __builtin_amdgcn_fdot2(__builtin_bit_cast(h2v, a),
                                  __builtin_bit_cast(h2v, b), c, false);
}

#define X4   (B_ * D_ / 4)
#define MEM4 (C_ * D_ / 4)
#define W4   (TWOD * TWOD / 4)
#define P24  (P_ * TWOD / 4)
#define P14  (TWOD / 4)
#define TOT4 (X4 + MEM4 + W4 + P24 + P14)

#define GRID_ 512

// ---------------------------------------------------------------------------
// Cooperative mega-kernel: all 6 former dispatches as phases with grid.sync.
// 512 blocks x 256 threads, 2 blocks/CU co-resident.
// ---------------------------------------------------------------------------
__global__ __launch_bounds__(256, 2) void mega(
    const float* __restrict__ x, const int* __restrict__ lb,
    const float* __restrict__ mem, const float* __restrict__ fcw,
    const float* __restrict__ fcb, const float* __restrict__ p1w,
    const float* __restrict__ p1b, const float* __restrict__ p2w,
    const float* __restrict__ p2b, float* __restrict__ ws,
    float* __restrict__ out)
{
    __shared__ __align__(16) char smem[46080];
    cg::grid_group grid = cg::this_grid();
    const int id = blockIdx.x;
    const int t  = threadIdx.x;

    ushort* mh       = (ushort*)(ws + OFF_MH);
    ushort* xh       = (ushort*)(ws + OFF_XH);
    float*  partial  = ws + OFF_PARTIAL;
    ushort* uhf      = (ushort*)(ws + OFF_UHF);
    float*  sqn      = ws + OFF_SQN;
    float*  clsbuf   = ws + OFF_CLS;
    float*  pairpart = ws + OFF_PAIR;
    ushort* xbf      = (ushort*)(ws + OFF_XBF);
    ushort* membf    = (ushort*)(ws + OFF_MEMBF);
    ushort* wbf      = (ushort*)(ws + OFF_WBF);
    ushort* p2h      = (ushort*)(ws + OFF_P2H);
    ushort* p1h      = (ushort*)(ws + OFF_P1H);

    // ================= P0: dtype conversions (grid-stride) =================
    for (int i = id * 256 + t; i < TOT4; i += GRID_ * 256) {
        const float* src; ushort* dst; int off; bool bf;
        if (i < X4)                        { src = x;   dst = xbf;   off = i; bf = true; }
        else if (i < X4 + MEM4)            { src = mem; dst = membf; off = i - X4; bf = true; }
        else if (i < X4 + MEM4 + W4)       { src = fcw; dst = wbf;   off = i - X4 - MEM4; bf = true; }
        else if (i < X4 + MEM4 + W4 + P24) { src = p2w; dst = p2h;   off = i - X4 - MEM4 - W4; bf = false; }
        else                               { src = p1w; dst = p1h;   off = i - X4 - MEM4 - W4 - P24; bf = false; }
        float4 v = ((const float4*)src)[off];
        ushort4 o;
        if (bf) { o.x = f2bf(v.x); o.y = f2bf(v.y); o.z = f2bf(v.z); o.w = f2bf(v.w); }
        else    { o.x = f2h(v.x);  o.y = f2h(v.y);  o.z = f2h(v.z);  o.w = f2h(v.w); }
        ((ushort4*)dst)[off] = o;
    }

    grid.sync();

    // ================= P1: merged GEMM (228 jobs) =========================
    if (id < 228) {
        ushort* As = (ushort*)smem;             // 64 x ASTR
        ushort* Bs = (ushort*)(smem + 5120);    // 128 x ASTR

        const ushort* A; ushort* Out; int M, m0, n0, koff; bool xblk;
        if (id < 192) {
            xblk = true;  A = xbf;   Out = xh; M = B_;
            m0 = (id & 15) * 64; n0 = (id >> 4) * 128; koff = 0;
        } else {
            int q = id - 192;
            xblk = false; A = membf; Out = mh; M = C_;
            m0 = (q % 3) * 64; n0 = (q / 3) * 128; koff = D_;
        }

        const int wave = t >> 6, lane = t & 63;
        const int wm = (wave & 1) * 32, wn = (wave >> 1) * 64;
        const int fm = lane & 15, quad = lane >> 4;

        const int row_a = t >> 2, qa = (t & 3) * 8;
        const int ar = min(m0 + row_a, M - 1);
        const ushort* Arow = A + (size_t)ar * D_ + qa;
        const ushort* Brow = wbf + (size_t)(n0 + row_a) * TWOD + koff + qa;

        f32x4 acc[2][4];
#pragma unroll
        for (int j = 0; j < 4; ++j) {
            float bv = xblk ? fcb[n0 + wn + j * 16 + fm] : 0.f;
#pragma unroll
            for (int i = 0; i < 2; ++i)
                acc[i][j] = (f32x4){bv, bv, bv, bv};
        }

        uint4 pa  = *(const uint4*)(Arow);
        uint4 pb0 = *(const uint4*)(Brow);
        uint4 pb1 = *(const uint4*)(Brow + 64 * TWOD);

        for (int k0 = 0; k0 < D_; k0 += 32) {
            __syncthreads();
            *(uint4*)&As[row_a * ASTR + qa] = pa;
            *(uint4*)&Bs[row_a * ASTR + qa] = pb0;
            *(uint4*)&Bs[(64 + row_a) * ASTR + qa] = pb1;
            __syncthreads();
            if (k0 + 32 < D_) {
                pa  = *(const uint4*)(Arow + k0 + 32);
                pb0 = *(const uint4*)(Brow + k0 + 32);
                pb1 = *(const uint4*)(Brow + 64 * TWOD + k0 + 32);
            }
            bfx8 af[2], bf[4];
#pragma unroll
            for (int i = 0; i < 2; ++i)
                af[i] = *(const bfx8*)&As[(wm + i * 16 + fm) * ASTR + quad * 8];
#pragma unroll
            for (int j = 0; j < 4; ++j)
                bf[j] = *(const bfx8*)&Bs[(wn + j * 16 + fm) * ASTR + quad * 8];
#pragma unroll
            for (int i = 0; i < 2; ++i)
#pragma unroll
                for (int j = 0; j < 4; ++j)
                    acc[i][j] = __builtin_amdgcn_mfma_f32_16x16x32_bf16(
                        af[i], bf[j], acc[i][j], 0, 0, 0);
        }

#pragma unroll
        for (int i = 0; i < 2; ++i)
#pragma unroll
            for (int j = 0; j < 4; ++j)
#pragma unroll
                for (int r = 0; r < 4; ++r) {
                    int row = m0 + wm + i * 16 + quad * 4 + r;
                    int col = n0 + wn + j * 16 + fm;
                    if (row < M) Out[(size_t)row * TWOD + col] = f2h(acc[i][j][r]);
                }
    }

    grid.sync();

    // ================= P2: fused tile (512 jobs, R8 layout) ================
    {
        const int bx = id & 7, yy = (id >> 3) & 3, z = id >> 5;
        const int b0 = bx * 128;
        const int e0 = z * ECHUNK;

        if (yy == 3) {
            // -------- MFMA f16 u-projection path --------
            ushort* Au = (ushort*)smem;                 // 128 x USTRU
            ushort* Wu = (ushort*)(smem + 30720);       // 64 x USTRU
            const int wave = t >> 6, lane = t & 63;
            const int fm = lane & 15, quad = lane >> 4;

            {   // stage relu(xh) f16 : 128 rows x 96 k
                const int row = t >> 1, kh = (t & 1) * 48;
                const ushort* src = xh + (size_t)(b0 + row) * TWOD + e0 + kh;
                uint4 v[6];
#pragma unroll
                for (int i = 0; i < 6; ++i) v[i] = *(const uint4*)&src[i * 8];
#pragma unroll
                for (int i = 0; i < 6; ++i) {
                    v[i].x = relu2(v[i].x); v[i].y = relu2(v[i].y);
                    v[i].z = relu2(v[i].z); v[i].w = relu2(v[i].w);
                    *(uint4*)&Au[row * USTRU + kh + i * 8] = v[i];
                }
            }
            {   // stage p2 f16 : 64 rows x 96 k
                const int row = t >> 2, ks = (t & 3) * 24;
                const ushort* pw = p2h + (size_t)row * TWOD + e0 + ks;
#pragma unroll
                for (int i = 0; i < 3; ++i)
                    *(uint4*)&Wu[row * USTRU + ks + i * 8] = *(const uint4*)&pw[i * 8];
            }
            __syncthreads();

            f32x4 uacc[2][4];
#pragma unroll
            for (int i = 0; i < 2; ++i)
#pragma unroll
                for (int j = 0; j < 4; ++j) uacc[i][j] = (f32x4){0.f, 0.f, 0.f, 0.f};
#pragma unroll
            for (int k0 = 0; k0 < ECHUNK; k0 += 32) {
                fp16x8 af[2], bf[4];
#pragma unroll
                for (int i = 0; i < 2; ++i)
                    af[i] = *(const fp16x8*)&Au[(wave * 32 + i * 16 + fm) * USTRU + k0 + quad * 8];
#pragma unroll
                for (int j = 0; j < 4; ++j)
                    bf[j] = *(const fp16x8*)&Wu[(j * 16 + fm) * USTRU + k0 + quad * 8];
#pragma unroll
                for (int i = 0; i < 2; ++i)
#pragma unroll
                    for (int j = 0; j < 4; ++j)
                        uacc[i][j] = __builtin_amdgcn_mfma_f32_16x16x32_f16(
                            af[i], bf[j], uacc[i][j], 0, 0, 0);
            }
#pragma unroll
            for (int i = 0; i < 2; ++i)
#pragma unroll
                for (int j = 0; j < 4; ++j)
#pragma unroll
                    for (int r = 0; r < 4; ++r) {
                        int row = b0 + wave * 32 + i * 16 + quad * 4 + r;
                        partial[((size_t)z * B_ + row) * CPAD + 192 + j * 16 + fm] =
                            uacc[i][j][r];
                    }
        } else {
            // -------- elementwise f16 path --------
            unsigned* xT = (unsigned*)smem;             // [48 ep][128 b]
            unsigned* mT = (unsigned*)(smem + 24576);   // [48][64 c]
            unsigned* wT = (unsigned*)(smem + 36864);   // [48]
            const int c0 = yy * 64;
            const int tm = t & 15, tn = t >> 4;

            {   // stage x: 2 thr/row, 48 halves each
                const int row = t >> 1, ph = (t & 1) * 48;
                const ushort* src = xh + (size_t)(b0 + row) * TWOD + e0 + ph;
                uint4 v[6];
#pragma unroll
                for (int i = 0; i < 6; ++i) v[i] = *(const uint4*)&src[i * 8];
#pragma unroll
                for (int i = 0; i < 6; ++i) {
                    const int ep = (t & 1) * 24 + i * 4;
                    xT[(ep + 0) * 128 + row] = v[i].x;
                    xT[(ep + 1) * 128 + row] = v[i].y;
                    xT[(ep + 2) * 128 + row] = v[i].z;
                    xT[(ep + 3) * 128 + row] = v[i].w;
                }
            }
            {   // stage m: 4 thr/col, 24 halves each
                const int col = t & 63, seg = t >> 6;
                const int gc  = c0 + col;
                uint4 v[3];
                if (gc < C_) {
                    const ushort* src = mh + (size_t)gc * TWOD + e0 + seg * 24;
#pragma unroll
                    for (int i = 0; i < 3; ++i) v[i] = *(const uint4*)&src[i * 8];
                } else {
#pragma unroll
                    for (int i = 0; i < 3; ++i) v[i] = make_uint4(0, 0, 0, 0);
                }
#pragma unroll
                for (int i = 0; i < 3; ++i) {
                    const int ep = seg * 12 + i * 4;
                    mT[(ep + 0) * 64 + col] = v[i].x;
                    mT[(ep + 1) * 64 + col] = v[i].y;
                    mT[(ep + 2) * 64 + col] = v[i].z;
                    mT[(ep + 3) * 64 + col] = v[i].w;
                }
            }
            if (t < 12) {  // stage w (p1): 96 halves
                uint4 v = *(const uint4*)&p1h[e0 + t * 8];
                wT[t * 4 + 0] = v.x; wT[t * 4 + 1] = v.y;
                wT[t * 4 + 2] = v.z; wT[t * 4 + 3] = v.w;
            }
            __syncthreads();

            float acc[8][4] = {};
#pragma unroll 4
            for (int ep = 0; ep < 48; ++ep) {
                uint4 a0 = *(const uint4*)&xT[ep * 128 + tm * 8];
                uint4 a1 = *(const uint4*)&xT[ep * 128 + tm * 8 + 4];
                uint4 mj = *(const uint4*)&mT[ep * 64 + tn * 4];
                const unsigned wv = wT[ep];
                const unsigned aa[8] = {a0.x, a0.y, a0.z, a0.w,
                                        a1.x, a1.y, a1.z, a1.w};
                const unsigned mm[4] = {mj.x, mj.y, mj.z, mj.w};
#pragma unroll
                for (int i = 0; i < 8; ++i)
#pragma unroll
                    for (int j = 0; j < 4; ++j)
                        acc[i][j] = dot2acc(addrelu2(aa[i], mm[j]), wv, acc[i][j]);
            }

#pragma unroll
            for (int i = 0; i < 8; ++i) {
                const int gb = b0 + tm * 8 + i;
                float4 v = make_float4(acc[i][0], acc[i][1], acc[i][2], acc[i][3]);
                *(float4*)&partial[((size_t)z * B_ + gb) * CPAD + c0 + tn * 4] = v;
            }
        }
    }

    grid.sync();

    // ================= P3: reduce rows (2 per block) ======================
    {
        float* sval = (float*)smem;
        for (int rr = 0; rr < 2; ++rr) {
            const int b = id * 2 + rr;
            float v = 0.f;
#pragma unroll
            for (int z = 0; z < ECHUNKS; ++z)
                v += partial[((size_t)z * B_ + b) * CPAD + t];
            if (t < NCLS)       v += p1b[0];
            else if (t >= 192)  v += p2b[t - 192];

            __syncthreads();   // sval free from previous iteration
            sval[t] = v;
            __syncthreads();

            if (t < 64) {
                float uv = sval[192 + t];
                float s = uv * uv;
#pragma unroll
                for (int off = 32; off; off >>= 1) s += __shfl_xor(s, off);
                float inv = 1.f / fmaxf(sqrtf(s), 1e-12f);
                uhf[(size_t)b * P_ + t] = f2h(uv * inv);
                if (t == 0) sqn[b] = s * inv * inv;

                const int l = lb[b];
                float mx = -1e30f;
                for (int j = t; j < NCLS; j += 64)
                    if (!(j == l && l < C_)) mx = fmaxf(mx, sval[j]);
#pragma unroll
                for (int off = 32; off; off >>= 1) mx = fmaxf(mx, __shfl_xor(mx, off));
                float se = 0.f;
                for (int j = t; j < NCLS; j += 64)
                    if (!(j == l && l < C_)) se += expf(sval[j] - mx);
#pragma unroll
                for (int off = 32; off; off >>= 1) se += __shfl_xor(se, off);

                if (t == 0) {
                    float l150  = sval[C_];
                    float loss2 = mx + logf(se) - l150;
                    float loss1 = 0.f;
                    if (l < C_) {
                        float a  = sval[l];
                        float m2 = fmaxf(a, l150);
                        loss1 = m2 - a + logf(expf(a - m2) + expf(l150 - m2));
                    }
                    clsbuf[b] = loss1 + loss2;
                }
            }
        }
    }

    grid.sync();

    // ================= P4: pairwise margin losses (256 jobs) ==============
    if (id < 256) {
        ushort* ui_s = (ushort*)smem;               // 64 x USTR
        ushort* uj_s = (ushort*)(smem + 9216);      // 64 x USTR
        float*  sni  = (float*)(smem + 18432);
        float*  snj  = (float*)(smem + 18688);
        int*    li   = (int*)(smem + 18944);
        int*    lj   = (int*)(smem + 19200);
        float*  red  = (float*)(smem + 19456);      // [4][4]

        const int i0 = (id & 15) * 64, j0 = (id >> 4) * 64;

        for (int idx = t; idx < 512; idx += 256) {
            int row = idx >> 3, ch = (idx & 7) * 8;
            *(uint4*)&ui_s[row * USTR + ch] =
                *(const uint4*)&uhf[(size_t)(i0 + row) * P_ + ch];
            *(uint4*)&uj_s[row * USTR + ch] =
                *(const uint4*)&uhf[(size_t)(j0 + row) * P_ + ch];
        }
        if (t < 64)       { sni[t] = sqn[i0 + t]; li[t] = lb[i0 + t]; }
        else if (t < 128) { int q = t - 64; snj[q] = sqn[j0 + q]; lj[q] = lb[j0 + q]; }
        __syncthreads();

        const int wave = t >> 6, lane = t & 63;
        const int n = lane & 15, quad = lane >> 4;
        const int iw = wave * 16;

        const fp16x8 af0 = *(const fp16x8*)&ui_s[(iw + n) * USTR + quad * 8];
        const fp16x8 af1 = *(const fp16x8*)&ui_s[(iw + n) * USTR + quad * 8 + 32];

        f32x4 acc[4];
#pragma unroll
        for (int jt = 0; jt < 4; ++jt) {
            const fp16x8 bf0 = *(const fp16x8*)&uj_s[(jt * 16 + n) * USTR + quad * 8];
            const fp16x8 bf1 = *(const fp16x8*)&uj_s[(jt * 16 + n) * USTR + quad * 8 + 32];
            acc[jt] = __builtin_amdgcn_mfma_f32_16x16x32_f16(
                af0, bf0, (f32x4){0.f, 0.f, 0.f, 0.f}, 0, 0, 0);
            acc[jt] = __builtin_amdgcn_mfma_f32_16x16x32_f16(
                af1, bf1, acc[jt], 0, 0, 0);
        }

        float ps = 0.f, pc = 0.f, ns = 0.f, nc = 0.f;
#pragma unroll
        for (int jt = 0; jt < 4; ++jt)
#pragma unroll
            for (int r = 0; r < 4; ++r) {
                const int il = iw + quad * 4 + r;
                const int jl = jt * 16 + n;
                float sq = sni[il] + snj[jl] - 2.f * acc[jt][r];
                float dist = sq > 0.f ? sqrtf(fmaxf(sq, 1e-16f)) : 0.f;
                bool same = (li[il] == lj[jl]);
                if (same) {
                    if (i0 + il != j0 + jl) { ps += fmaxf(dist - 0.7f, 0.f); pc += 1.f; }
                } else {
                    ns += fmaxf(1.4f - dist, 0.f); nc += 1.f;
                }
            }

#pragma unroll
        for (int off = 32; off; off >>= 1) {
            ps += __shfl_xor(ps, off); pc += __shfl_xor(pc, off);
            ns += __shfl_xor(ns, off); nc += __shfl_xor(nc, off);
        }
        if (lane == 0) { red[0 * 4 + wave] = ps; red[1 * 4 + wave] = pc;
                         red[2 * 4 + wave] = ns; red[3 * 4 + wave] = nc; }
        __syncthreads();
        if (t == 0) {
            float4 v;
            v.x = red[0] + red[1] + red[2] + red[3];
            v.y = red[4] + red[5] + red[6] + red[7];
            v.z = red[8] + red[9] + red[10] + red[11];
            v.w = red[12] + red[13] + red[14] + red[15];
            *(float4*)&pairpart[(size_t)id * 4] = v;
        }
    }

    grid.sync();

    // ================= P5: finalize (block 0) =============================
    if (id == 0) {
        float* red = (float*)smem;   // [5][4]
        float c = clsbuf[t] + clsbuf[t + 256] + clsbuf[t + 512] + clsbuf[t + 768];
        float4 pp = *(const float4*)&pairpart[(size_t)t * 4];
        float ps = pp.x, pc = pp.y, ns = pp.z, nc = pp.w;
#pragma unroll
        for (int off = 32; off; off >>= 1) {
            c  += __shfl_xor(c, off);
            ps += __shfl_xor(ps, off); pc += __shfl_xor(pc, off);
            ns += __shfl_xor(ns, off); nc += __shfl_xor(nc, off);
        }
        const int wave = t >> 6, lane = t & 63;
        __syncthreads();   // smem reuse after P4
        if (lane == 0) { red[0 * 4 + wave] = c; red[1 * 4 + wave] = ps;
                         red[2 * 4 + wave] = pc; red[3 * 4 + wave] = ns;
                         red[4 * 4 + wave] = nc; }
        __syncthreads();
        if (t == 0) {
            float C = 0.f, PS = 0.f, PC = 0.f, NS = 0.f, NC = 0.f;
#pragma unroll
            for (int w = 0; w < 4; ++w) {
                C += red[0 * 4 + w]; PS += red[1 * 4 + w]; PC += red[2 * 4 + w];
                NS += red[3 * 4 + w]; NC += red[4 * 4 + w];
            }
            out[0] = C / (float)B_ + PS / fmaxf(PC, 1.f) + NS / fmaxf(NC, 1.f);
        }
    }
}

extern "C" void kernel_launch(void* const* d_in, const int* in_sizes, int n_in,
                              void* d_out, int out_size, void* d_ws, size_t ws_size,
                              hipStream_t stream)
{
    const float* x    = (const float*)d_in[0];
    const int*   lb   = (const int*)d_in[1];
    const float* mem  = (const float*)d_in[2];
    const float* fc_w = (const float*)d_in[3];
    const float* fc_b = (const float*)d_in[4];
    const float* p1w  = (const float*)d_in[5];
    const float* p1b  = (const float*)d_in[6];
    const float* p2w  = (const float*)d_in[7];
    const float* p2b  = (const float*)d_in[8];
    float* ws  = (float*)d_ws;
    float* out = (float*)d_out;

    void* args[] = {
        (void*)&x, (void*)&lb, (void*)&mem, (void*)&fc_w, (void*)&fc_b,
        (void*)&p1w, (void*)&p1b, (void*)&p2w, (void*)&p2b,
        (void*)&ws, (void*)&out
    };
    hipLaunchCooperativeKernel((void*)mega, dim3(GRID_), dim3(256),
                               args, 0, stream);
}

// Round 11
// 139.784 us; speedup vs baseline: 2.8892x; 2.8892x over previous
//
#include <hip/hip_runtime.h>
#include <math.h>

// Problem constants
#define B_    1024
#define D_    768
#define C_    150
#define P_    64
#define TWOD  1536
#define NCLS  151   // C+1
#define CPAD  256   // partial row: 0..150 logits, 151..191 junk, 192..255 u

// fused_tile: 128b x 64c per block, 8x4/thr, e split 16 ways (R8-proven)
#define ECHUNKS 16
#define ECHUNK  96

#define ASTR  40    // gemm LDS stride (bf16)
#define USTRU 120   // u-path LDS stride (halves)
#define USTR  72    // pair_loss LDS stride (halves)

// Workspace layout (float offsets)
#define OFF_MH      0                                   // half[150*1536]
#define OFF_XH      (OFF_MH + (C_ * TWOD) / 2)          // half[1024*1536]
#define OFF_PARTIAL (OFF_XH + (B_ * TWOD) / 2)          // fp32[16*1024*256]
#define OFF_UHF     (OFF_PARTIAL + ECHUNKS * B_ * CPAD) // half[1024*64]
#define OFF_SQN     (OFF_UHF + (B_ * P_) / 2)
#define OFF_CLS     (OFF_SQN + B_)
#define OFF_PAIR    (OFF_CLS + B_)
#define OFF_CTR     (OFF_PAIR + 1024)
#define OFF_P2H     (OFF_CTR + 4)                       // half[64*1536]
#define OFF_P1H     (OFF_P2H + (P_ * TWOD) / 2)         // half[1536]
// end ~5.1M floats ~ 20.5 MB

typedef __bf16    bfx8   __attribute__((ext_vector_type(8)));
typedef _Float16  fp16x8 __attribute__((ext_vector_type(8)));
typedef _Float16  h2v    __attribute__((ext_vector_type(2)));
typedef float     f32x4  __attribute__((ext_vector_type(4)));

__device__ inline ushort f2bf(float f) {
    union { float f; unsigned u; } c; c.f = f;
    unsigned r = c.u + 0x7fffu + ((c.u >> 16) & 1u);
    return (ushort)(r >> 16);
}
__device__ inline ushort f2h(float f) {
    _Float16 h = (_Float16)f;
    return __builtin_bit_cast(ushort, h);
}
__device__ inline unsigned addrelu2(unsigned a, unsigned m) {
    h2v s = __builtin_bit_cast(h2v, a) + __builtin_bit_cast(h2v, m);
    h2v z = {(_Float16)0.f, (_Float16)0.f};
    s = __builtin_elementwise_max(s, z);
    return __builtin_bit_cast(unsigned, s);
}
__device__ inline unsigned relu2(unsigned a) {
    h2v s = __builtin_bit_cast(h2v, a);
    h2v z = {(_Float16)0.f, (_Float16)0.f};
    s = __builtin_elementwise_max(s, z);
    return __builtin_bit_cast(unsigned, s);
}
__device__ inline float dot2acc(unsigned a, unsigned b, float c) {
    return __builtin_amdgcn_fdot2(__builtin_bit_cast(h2v, a),
                                  __builtin_bit_cast(h2v, b), c, false);
}
__device__ inline uint4 cvt8bf(float4 a, float4 b) {
    ushort o[8];
    o[0] = f2bf(a.x); o[1] = f2bf(a.y); o[2] = f2bf(a.z); o[3] = f2bf(a.w);
    o[4] = f2bf(b.x); o[5] = f2bf(b.y); o[6] = f2bf(b.z); o[7] = f2bf(b.w);
    return *(const uint4*)&o[0];
}

#define P24  (P_ * TWOD / 4)   // p2w float4 count
#define P14  (TWOD / 4)        // p1w float4 count

// ---------------------------------------------------------------------------
// K1: merged MFMA GEMM + side conversions.
// ids [0,192): xh = x @ Wx^T + fc_b ; ids [192,228): mh = mem @ Wm^T
//   (fp32 in, in-register bf16 staging, f16 out; 64x128 tile, BK=32)
// ids [228,241): convert p2w/p1w -> f16 ; id 228 zeros the pair counter.
// ---------------------------------------------------------------------------
__global__ __launch_bounds__(256) void gemm_all(
    const float* __restrict__ xf, const float* __restrict__ memf,
    const float* __restrict__ fcw, const float* __restrict__ fc_b,
    const float* __restrict__ p2w, const float* __restrict__ p1w,
    ushort* __restrict__ xh, ushort* __restrict__ mh,
    ushort* __restrict__ p2h, ushort* __restrict__ p1h,
    int* __restrict__ ctr)
{
    const int id = blockIdx.x;
    const int t  = threadIdx.x;

    if (id >= 228) {
        // side job: p2w/p1w -> f16, zero counter
        if (id == 228 && t == 0) *ctr = 0;
        const int cid = id - 228;
        for (int i = cid * 256 + t; i < P24 + P14; i += 13 * 256) {
            const float* src; ushort* dst; int off;
            if (i < P24) { src = p2w; dst = p2h; off = i; }
            else         { src = p1w; dst = p1h; off = i - P24; }
            float4 v = ((const float4*)src)[off];
            ushort4 o;
            o.x = f2h(v.x); o.y = f2h(v.y); o.z = f2h(v.z); o.w = f2h(v.w);
            ((ushort4*)dst)[off] = o;
        }
        return;
    }

    __shared__ ushort As[64 * ASTR];
    __shared__ ushort Bs[128 * ASTR];

    const float* A; ushort* Out; int M, m0, n0, koff; bool xblk;
    if (id < 192) {
        xblk = true;  A = xf;   Out = xh; M = B_;
        m0 = (id & 15) * 64; n0 = (id >> 4) * 128; koff = 0;
    } else {
        int q = id - 192;
        xblk = false; A = memf; Out = mh; M = C_;
        m0 = (q % 3) * 64; n0 = (q / 3) * 128; koff = D_;
    }

    const int wave = t >> 6, lane = t & 63;
    const int wm = (wave & 1) * 32, wn = (wave >> 1) * 64;
    const int fm = lane & 15, quad = lane >> 4;

    const int row_a = t >> 2, qa = (t & 3) * 8;
    const int ar = min(m0 + row_a, M - 1);
    const float* Arow  = A + (size_t)ar * D_ + qa;
    const float* Brow0 = fcw + (size_t)(n0 + row_a) * TWOD + koff + qa;
    const float* Brow1 = Brow0 + (size_t)64 * TWOD;

    f32x4 acc[2][4];
#pragma unroll
    for (int j = 0; j < 4; ++j) {
        float bv = xblk ? fc_b[n0 + wn + j * 16 + fm] : 0.f;
#pragma unroll
        for (int i = 0; i < 2; ++i)
            acc[i][j] = (f32x4){bv, bv, bv, bv};
    }

    float4 pa0  = *(const float4*)(Arow),   pa1  = *(const float4*)(Arow + 4);
    float4 pb00 = *(const float4*)(Brow0),  pb01 = *(const float4*)(Brow0 + 4);
    float4 pb10 = *(const float4*)(Brow1),  pb11 = *(const float4*)(Brow1 + 4);

    for (int k0 = 0; k0 < D_; k0 += 32) {
        uint4 va  = cvt8bf(pa0, pa1);
        uint4 vb0 = cvt8bf(pb00, pb01);
        uint4 vb1 = cvt8bf(pb10, pb11);
        __syncthreads();   // prev frag reads done
        *(uint4*)&As[row_a * ASTR + qa] = va;
        *(uint4*)&Bs[row_a * ASTR + qa] = vb0;
        *(uint4*)&Bs[(64 + row_a) * ASTR + qa] = vb1;
        __syncthreads();
        if (k0 + 32 < D_) {
            pa0  = *(const float4*)(Arow + k0 + 32);
            pa1  = *(const float4*)(Arow + k0 + 36);
            pb00 = *(const float4*)(Brow0 + k0 + 32);
            pb01 = *(const float4*)(Brow0 + k0 + 36);
            pb10 = *(const float4*)(Brow1 + k0 + 32);
            pb11 = *(const float4*)(Brow1 + k0 + 36);
        }
        bfx8 af[2], bf[4];
#pragma unroll
        for (int i = 0; i < 2; ++i)
            af[i] = *(const bfx8*)&As[(wm + i * 16 + fm) * ASTR + quad * 8];
#pragma unroll
        for (int j = 0; j < 4; ++j)
            bf[j] = *(const bfx8*)&Bs[(wn + j * 16 + fm) * ASTR + quad * 8];
#pragma unroll
        for (int i = 0; i < 2; ++i)
#pragma unroll
            for (int j = 0; j < 4; ++j)
                acc[i][j] = __builtin_amdgcn_mfma_f32_16x16x32_bf16(
                    af[i], bf[j], acc[i][j], 0, 0, 0);
    }

#pragma unroll
    for (int i = 0; i < 2; ++i)
#pragma unroll
        for (int j = 0; j < 4; ++j)
#pragma unroll
            for (int r = 0; r < 4; ++r) {
                int row = m0 + wm + i * 16 + quad * 4 + r;
                int col = n0 + wn + j * 16 + fm;
                if (row < M) Out[(size_t)row * TWOD + col] = f2h(acc[i][j][r]);
            }
}

// ---------------------------------------------------------------------------
// K2: fused tile (f16) — exact R8 body.
// y<3: elementwise partial[z][b][c] = sum relu(xh+m)*p1 (pk_f16 + dot2).
// y==3: MFMA f16 u-projection partial[z][b][192+n] = sum relu(xh)*p2.
// ---------------------------------------------------------------------------
__global__ __launch_bounds__(256) void fused_tile(
    const ushort* __restrict__ xh, const ushort* __restrict__ mh,
    const ushort* __restrict__ p1h, const ushort* __restrict__ p2h,
    float* __restrict__ partial)
{
    __shared__ __align__(16) char smem[46080];
    const int t  = threadIdx.x;
    const int b0 = blockIdx.x * 128;
    const int z  = blockIdx.z;
    const int e0 = z * ECHUNK;

    if (blockIdx.y == 3) {
        ushort* Au = (ushort*)smem;                 // 128 x USTRU halves
        ushort* Wu = (ushort*)(smem + 30720);       // 64 x USTRU halves
        const int wave = t >> 6, lane = t & 63;
        const int fm = lane & 15, quad = lane >> 4;

        {   // stage relu(xh) f16 : 128 rows x 96 k
            const int row = t >> 1, kh = (t & 1) * 48;
            const ushort* src = xh + (size_t)(b0 + row) * TWOD + e0 + kh;
            uint4 v[6];
#pragma unroll
            for (int i = 0; i < 6; ++i) v[i] = *(const uint4*)&src[i * 8];
#pragma unroll
            for (int i = 0; i < 6; ++i) {
                v[i].x = relu2(v[i].x); v[i].y = relu2(v[i].y);
                v[i].z = relu2(v[i].z); v[i].w = relu2(v[i].w);
                *(uint4*)&Au[row * USTRU + kh + i * 8] = v[i];
            }
        }
        {   // stage p2 f16 : 64 rows x 96 k
            const int row = t >> 2, ks = (t & 3) * 24;
            const ushort* pw = p2h + (size_t)row * TWOD + e0 + ks;
#pragma unroll
            for (int i = 0; i < 3; ++i)
                *(uint4*)&Wu[row * USTRU + ks + i * 8] = *(const uint4*)&pw[i * 8];
        }
        __syncthreads();

        f32x4 uacc[2][4];
#pragma unroll
        for (int i = 0; i < 2; ++i)
#pragma unroll
            for (int j = 0; j < 4; ++j) uacc[i][j] = (f32x4){0.f, 0.f, 0.f, 0.f};
#pragma unroll
        for (int k0 = 0; k0 < ECHUNK; k0 += 32) {
            fp16x8 af[2], bf[4];
#pragma unroll
            for (int i = 0; i < 2; ++i)
                af[i] = *(const fp16x8*)&Au[(wave * 32 + i * 16 + fm) * USTRU + k0 + quad * 8];
#pragma unroll
            for (int j = 0; j < 4; ++j)
                bf[j] = *(const fp16x8*)&Wu[(j * 16 + fm) * USTRU + k0 + quad * 8];
#pragma unroll
            for (int i = 0; i < 2; ++i)
#pragma unroll
                for (int j = 0; j < 4; ++j)
                    uacc[i][j] = __builtin_amdgcn_mfma_f32_16x16x32_f16(
                        af[i], bf[j], uacc[i][j], 0, 0, 0);
        }
#pragma unroll
        for (int i = 0; i < 2; ++i)
#pragma unroll
            for (int j = 0; j < 4; ++j)
#pragma unroll
                for (int r = 0; r < 4; ++r) {
                    int row = b0 + wave * 32 + i * 16 + quad * 4 + r;
                    partial[((size_t)z * B_ + row) * CPAD + 192 + j * 16 + fm] =
                        uacc[i][j][r];
                }
        return;
    }

    // -------- elementwise f16 path: cols c0..c0+63 (c0 in {0,64,128}) -----
    unsigned* xT = (unsigned*)smem;             // [48 e-pairs][128 b]
    unsigned* mT = (unsigned*)(smem + 24576);   // [48][64 c]
    unsigned* wT = (unsigned*)(smem + 36864);   // [48]
    const int c0 = blockIdx.y * 64;
    const int tm = t & 15, tn = t >> 4;

    {   // stage x: 2 thr/row, 48 halves each
        const int row = t >> 1, ph = (t & 1) * 48;
        const ushort* src = xh + (size_t)(b0 + row) * TWOD + e0 + ph;
        uint4 v[6];
#pragma unroll
        for (int i = 0; i < 6; ++i) v[i] = *(const uint4*)&src[i * 8];
#pragma unroll
        for (int i = 0; i < 6; ++i) {
            const int ep = (t & 1) * 24 + i * 4;
            xT[(ep + 0) * 128 + row] = v[i].x;
            xT[(ep + 1) * 128 + row] = v[i].y;
            xT[(ep + 2) * 128 + row] = v[i].z;
            xT[(ep + 3) * 128 + row] = v[i].w;
        }
    }
    {   // stage m: 4 thr/col, 24 halves each
        const int col = t & 63, seg = t >> 6;
        const int gc  = c0 + col;
        uint4 v[3];
        if (gc < C_) {
            const ushort* src = mh + (size_t)gc * TWOD + e0 + seg * 24;
#pragma unroll
            for (int i = 0; i < 3; ++i) v[i] = *(const uint4*)&src[i * 8];
        } else {
#pragma unroll
            for (int i = 0; i < 3; ++i) v[i] = make_uint4(0, 0, 0, 0);
        }
#pragma unroll
        for (int i = 0; i < 3; ++i) {
            const int ep = seg * 12 + i * 4;
            mT[(ep + 0) * 64 + col] = v[i].x;
            mT[(ep + 1) * 64 + col] = v[i].y;
            mT[(ep + 2) * 64 + col] = v[i].z;
            mT[(ep + 3) * 64 + col] = v[i].w;
        }
    }
    if (t < 12) {  // stage w (p1): 96 halves
        uint4 v = *(const uint4*)&p1h[e0 + t * 8];
        wT[t * 4 + 0] = v.x; wT[t * 4 + 1] = v.y;
        wT[t * 4 + 2] = v.z; wT[t * 4 + 3] = v.w;
    }
    __syncthreads();

    float acc[8][4] = {};
#pragma unroll 4
    for (int ep = 0; ep < 48; ++ep) {
        uint4 a0 = *(const uint4*)&xT[ep * 128 + tm * 8];
        uint4 a1 = *(const uint4*)&xT[ep * 128 + tm * 8 + 4];
        uint4 mj = *(const uint4*)&mT[ep * 64 + tn * 4];
        const unsigned wv = wT[ep];
        const unsigned aa[8] = {a0.x, a0.y, a0.z, a0.w, a1.x, a1.y, a1.z, a1.w};
        const unsigned mm[4] = {mj.x, mj.y, mj.z, mj.w};
#pragma unroll
        for (int i = 0; i < 8; ++i)
#pragma unroll
            for (int j = 0; j < 4; ++j)
                acc[i][j] = dot2acc(addrelu2(aa[i], mm[j]), wv, acc[i][j]);
    }

#pragma unroll
    for (int i = 0; i < 8; ++i) {
        const int gb = b0 + tm * 8 + i;
        float4 v = make_float4(acc[i][0], acc[i][1], acc[i][2], acc[i][3]);
        *(float4*)&partial[((size_t)z * B_ + gb) * CPAD + c0 + tn * 4] = v;
    }
}

// ---------------------------------------------------------------------------
// K3: per-row reduce of partials + bias, u-normalize (-> f16) + cls loss.
// ---------------------------------------------------------------------------
__global__ __launch_bounds__(256) void reduce_row(
    const float* __restrict__ partial,
    const float* __restrict__ p1b, const float* __restrict__ p2b,
    const int* __restrict__ lb,
    ushort* __restrict__ uhf, float* __restrict__ sqn,
    float* __restrict__ clsbuf)
{
    const int b = blockIdx.x, t = threadIdx.x;
    float v = 0.f;
#pragma unroll
    for (int z = 0; z < ECHUNKS; ++z)
        v += partial[((size_t)z * B_ + b) * CPAD + t];
    if (t < NCLS)       v += p1b[0];
    else if (t >= 192)  v += p2b[t - 192];

    __shared__ float sval[256];
    sval[t] = v;
    __syncthreads();

    if (t < 64) {
        float uv = sval[192 + t];
        float s = uv * uv;
#pragma unroll
        for (int off = 32; off; off >>= 1) s += __shfl_xor(s, off);
        float inv = 1.f / fmaxf(sqrtf(s), 1e-12f);
        uhf[(size_t)b * P_ + t] = f2h(uv * inv);
        if (t == 0) sqn[b] = s * inv * inv;

        const int l = lb[b];
        float mx = -1e30f;
        for (int j = t; j < NCLS; j += 64)
            if (!(j == l && l < C_)) mx = fmaxf(mx, sval[j]);
#pragma unroll
        for (int off = 32; off; off >>= 1) mx = fmaxf(mx, __shfl_xor(mx, off));
        float se = 0.f;
        for (int j = t; j < NCLS; j += 64)
            if (!(j == l && l < C_)) se += expf(sval[j] - mx);
#pragma unroll
        for (int off = 32; off; off >>= 1) se += __shfl_xor(se, off);

        if (t == 0) {
            float l150  = sval[C_];
            float loss2 = mx + logf(se) - l150;
            float loss1 = 0.f;
            if (l < C_) {
                float a  = sval[l];
                float m2 = fmaxf(a, l150);
                loss1 = m2 - a + logf(expf(a - m2) + expf(l150 - m2));
            }
            clsbuf[b] = loss1 + loss2;
        }
    }
}

// ---------------------------------------------------------------------------
// K4: pairwise margin losses (f16 MFMA Gram) + last-block-done finalize.
// Grid flat 256 blocks (16x16 pair tiles).
// ---------------------------------------------------------------------------
__global__ __launch_bounds__(256) void pair_loss(
    const ushort* __restrict__ uhf, const float* __restrict__ sqn,
    const int* __restrict__ lb, const float* __restrict__ clsbuf,
    float* __restrict__ pairpart, int* __restrict__ ctr,
    float* __restrict__ out)
{
    __shared__ ushort ui_s[64 * USTR];
    __shared__ ushort uj_s[64 * USTR];
    __shared__ float sni[64], snj[64];
    __shared__ int   li[64],  lj[64];
    __shared__ float red[5][4];
    __shared__ int   isLast;

    const int t  = threadIdx.x;
    const int id = blockIdx.x;
    const int i0 = (id & 15) * 64, j0 = (id >> 4) * 64;

    for (int idx = t; idx < 512; idx += 256) {
        int row = idx >> 3, ch = (idx & 7) * 8;
        *(uint4*)&ui_s[row * USTR + ch] =
            *(const uint4*)&uhf[(size_t)(i0 + row) * P_ + ch];
        *(uint4*)&uj_s[row * USTR + ch] =
            *(const uint4*)&uhf[(size_t)(j0 + row) * P_ + ch];
    }
    if (t < 64)       { sni[t] = sqn[i0 + t]; li[t] = lb[i0 + t]; }
    else if (t < 128) { int q = t - 64; snj[q] = sqn[j0 + q]; lj[q] = lb[j0 + q]; }
    __syncthreads();

    const int wave = t >> 6, lane = t & 63;
    const int n = lane & 15, quad = lane >> 4;
    const int iw = wave * 16;

    const fp16x8 af0 = *(const fp16x8*)&ui_s[(iw + n) * USTR + quad * 8];
    const fp16x8 af1 = *(const fp16x8*)&ui_s[(iw + n) * USTR + quad * 8 + 32];

    f32x4 acc[4];
#pragma unroll
    for (int jt = 0; jt < 4; ++jt) {
        const fp16x8 bf0 = *(const fp16x8*)&uj_s[(jt * 16 + n) * USTR + quad * 8];
        const fp16x8 bf1 = *(const fp16x8*)&uj_s[(jt * 16 + n) * USTR + quad * 8 + 32];
        acc[jt] = __builtin_amdgcn_mfma_f32_16x16x32_f16(
            af0, bf0, (f32x4){0.f, 0.f, 0.f, 0.f}, 0, 0, 0);
        acc[jt] = __builtin_amdgcn_mfma_f32_16x16x32_f16(
            af1, bf1, acc[jt], 0, 0, 0);
    }

    float ps = 0.f, pc = 0.f, ns = 0.f, nc = 0.f;
#pragma unroll
    for (int jt = 0; jt < 4; ++jt)
#pragma unroll
        for (int r = 0; r < 4; ++r) {
            const int il = iw + quad * 4 + r;
            const int jl = jt * 16 + n;
            float sq = sni[il] + snj[jl] - 2.f * acc[jt][r];
            float dist = sq > 0.f ? sqrtf(fmaxf(sq, 1e-16f)) : 0.f;
            bool same = (li[il] == lj[jl]);
            if (same) {
                if (i0 + il != j0 + jl) { ps += fmaxf(dist - 0.7f, 0.f); pc += 1.f; }
            } else {
                ns += fmaxf(1.4f - dist, 0.f); nc += 1.f;
            }
        }

#pragma unroll
    for (int off = 32; off; off >>= 1) {
        ps += __shfl_xor(ps, off); pc += __shfl_xor(pc, off);
        ns += __shfl_xor(ns, off); nc += __shfl_xor(nc, off);
    }
    if (lane == 0) { red[0][wave] = ps; red[1][wave] = pc;
                     red[2][wave] = ns; red[3][wave] = nc; }
    __syncthreads();
    if (t == 0) {
        float4 v;
        v.x = red[0][0] + red[0][1] + red[0][2] + red[0][3];
        v.y = red[1][0] + red[1][1] + red[1][2] + red[1][3];
        v.z = red[2][0] + red[2][1] + red[2][2] + red[2][3];
        v.w = red[3][0] + red[3][1] + red[3][2] + red[3][3];
        *(float4*)&pairpart[(size_t)id * 4] = v;
        __threadfence();                       // release our partial
        int old = atomicAdd(ctr, 1);
        isLast = (old == 255);
    }
    __syncthreads();

    if (isLast) {
        __threadfence();                       // acquire all partials
        float c = clsbuf[t] + clsbuf[t + 256] + clsbuf[t + 512] + clsbuf[t + 768];
        float4 pp = *(const float4*)&pairpart[(size_t)t * 4];
        float fps = pp.x, fpc = pp.y, fns = pp.z, fnc = pp.w;
#pragma unroll
        for (int off = 32; off; off >>= 1) {
            c   += __shfl_xor(c, off);
            fps += __shfl_xor(fps, off); fpc += __shfl_xor(fpc, off);
            fns += __shfl_xor(fns, off); fnc += __shfl_xor(fnc, off);
        }
        __syncthreads();   // red[] reuse
        if (lane == 0) { red[0][wave] = c;   red[1][wave] = fps;
                         red[2][wave] = fpc; red[3][wave] = fns;
                         red[4][wave] = fnc; }
        __syncthreads();
        if (t == 0) {
            float C = 0.f, PS = 0.f, PC = 0.f, NS = 0.f, NC = 0.f;
#pragma unroll
            for (int w = 0; w < 4; ++w) {
                C += red[0][w]; PS += red[1][w]; PC += red[2][w];
                NS += red[3][w]; NC += red[4][w];
            }
            out[0] = C / (float)B_ + PS / fmaxf(PC, 1.f) + NS / fmaxf(NC, 1.f);
        }
    }
}

extern "C" void kernel_launch(void* const* d_in, const int* in_sizes, int n_in,
                              void* d_out, int out_size, void* d_ws, size_t ws_size,
                              hipStream_t stream)
{
    const float* x    = (const float*)d_in[0];
    const int*   lb   = (const int*)d_in[1];
    const float* mem  = (const float*)d_in[2];
    const float* fc_w = (const float*)d_in[3];
    const float* fc_b = (const float*)d_in[4];
    const float* p1w  = (const float*)d_in[5];
    const float* p1b  = (const float*)d_in[6];
    const float* p2w  = (const float*)d_in[7];
    const float* p2b  = (const float*)d_in[8];

    float* ws       = (float*)d_ws;
    ushort* mh      = (ushort*)(ws + OFF_MH);
    ushort* xh      = (ushort*)(ws + OFF_XH);
    float* partials = ws + OFF_PARTIAL;
    ushort* uhf     = (ushort*)(ws + OFF_UHF);
    float* sqn      = ws + OFF_SQN;
    float* clsbuf   = ws + OFF_CLS;
    float* pairpart = ws + OFF_PAIR;
    int*   ctr      = (int*)(ws + OFF_CTR);
    ushort* p2h     = (ushort*)(ws + OFF_P2H);
    ushort* p1h     = (ushort*)(ws + OFF_P1H);

    // K1: merged gemms (fp32 in, in-register bf16) + p1/p2 cvt + ctr zero
    gemm_all<<<241, 256, 0, stream>>>(x, mem, fc_w, fc_b, p2w, p1w,
                                      xh, mh, p2h, p1h, ctr);
    // K2: fused elementwise logits partials + MFMA f16 u-partials
    fused_tile<<<dim3(8, 4, ECHUNKS), 256, 0, stream>>>(xh, mh, p1h, p2h,
                                                        partials);
    // K3: reduce partials + bias, normalize u (f16), classification loss
    reduce_row<<<B_, 256, 0, stream>>>(partials, p1b, p2b, lb, uhf, sqn, clsbuf);
    // K4: pairwise margin losses + last-block finalize
    pair_loss<<<256, 256, 0, stream>>>(uhf, sqn, lb, clsbuf, pairpart, ctr,
                                       (float*)d_out);
}

// Round 12
// 137.907 us; speedup vs baseline: 2.9285x; 1.0136x over previous
//
#include <hip/hip_runtime.h>
#include <math.h>

// Problem constants
#define B_    1024
#define D_    768
#define C_    150
#define P_    64
#define TWOD  1536
#define NCLS  151   // C+1
#define CPAD  256   // partial row: 0..150 logits, 151..191 junk, 192..255 u

// fused_tile: 128b x 64c per block, 8x4/thr, e split 16 ways (R8-proven)
#define ECHUNKS 16
#define ECHUNK  96

#define ASTR  40    // gemm LDS stride (bf16)
#define USTRU 120   // u-path LDS stride (halves)
#define USTR  72    // pair_loss LDS stride (halves)

// Workspace layout (float offsets)
#define OFF_MH      0                                   // half[150*1536]
#define OFF_XH      (OFF_MH + (C_ * TWOD) / 2)          // half[1024*1536]
#define OFF_PARTIAL (OFF_XH + (B_ * TWOD) / 2)          // fp32[16*1024*256]
#define OFF_UHF     (OFF_PARTIAL + ECHUNKS * B_ * CPAD) // half[1024*64]
#define OFF_SQN     (OFF_UHF + (B_ * P_) / 2)
#define OFF_CLS     (OFF_SQN + B_)
#define OFF_PAIR    (OFF_CLS + B_)
#define OFF_CTR     (OFF_PAIR + 1024)
#define OFF_XBF     (OFF_CTR + 4)
#define OFF_MEMBF   (OFF_XBF + (B_ * D_) / 2)
#define OFF_WBF     (OFF_MEMBF + (C_ * D_) / 2)
#define OFF_P2H     (OFF_WBF + (TWOD * TWOD) / 2)
#define OFF_P1H     (OFF_P2H + (P_ * TWOD) / 2)
// end ~6.82M floats ~ 27.3 MB

typedef __bf16    bfx8   __attribute__((ext_vector_type(8)));
typedef _Float16  fp16x8 __attribute__((ext_vector_type(8)));
typedef _Float16  h2v    __attribute__((ext_vector_type(2)));
typedef float     f32x4  __attribute__((ext_vector_type(4)));

__device__ inline ushort f2bf(float f) {
    union { float f; unsigned u; } c; c.f = f;
    unsigned r = c.u + 0x7fffu + ((c.u >> 16) & 1u);
    return (ushort)(r >> 16);
}
__device__ inline ushort f2h(float f) {
    _Float16 h = (_Float16)f;
    return __builtin_bit_cast(ushort, h);
}
__device__ inline unsigned addrelu2(unsigned a, unsigned m) {
    h2v s = __builtin_bit_cast(h2v, a) + __builtin_bit_cast(h2v, m);
    h2v z = {(_Float16)0.f, (_Float16)0.f};
    s = __builtin_elementwise_max(s, z);
    return __builtin_bit_cast(unsigned, s);
}
__device__ inline unsigned relu2(unsigned a) {
    h2v s = __builtin_bit_cast(h2v, a);
    h2v z = {(_Float16)0.f, (_Float16)0.f};
    s = __builtin_elementwise_max(s, z);
    return __builtin_bit_cast(unsigned, s);
}
__device__ inline float dot2acc(unsigned a, unsigned b, float c) {
    return __builtin_amdgcn_fdot2(__builtin_bit_cast(h2v, a),
                                  __builtin_bit_cast(h2v, b), c, false);
}

// ---------------------------------------------------------------------------
// K0: fp32 -> bf16 (x, mem, fc_w) and fp32 -> f16 (p2w, p1w); zero ctr.
// ---------------------------------------------------------------------------
#define X4   (B_ * D_ / 4)
#define MEM4 (C_ * D_ / 4)
#define W4   (TWOD * TWOD / 4)
#define P24  (P_ * TWOD / 4)
#define P14  (TWOD / 4)
#define TOT4 (X4 + MEM4 + W4 + P24 + P14)

__global__ __launch_bounds__(256) void prep_cvt(
    const float* __restrict__ x, const float* __restrict__ mem,
    const float* __restrict__ w, const float* __restrict__ p2w,
    const float* __restrict__ p1w,
    ushort* __restrict__ xb, ushort* __restrict__ memb,
    ushort* __restrict__ wb, ushort* __restrict__ p2h,
    ushort* __restrict__ p1h, int* __restrict__ ctr)
{
    int i = blockIdx.x * 256 + threadIdx.x;
    if (i == 0) *ctr = 0;
    if (i >= TOT4) return;
    const float* src; ushort* dst; int off; bool bf;
    if (i < X4)                        { src = x;   dst = xb;   off = i; bf = true; }
    else if (i < X4 + MEM4)            { src = mem; dst = memb; off = i - X4; bf = true; }
    else if (i < X4 + MEM4 + W4)       { src = w;   dst = wb;   off = i - X4 - MEM4; bf = true; }
    else if (i < X4 + MEM4 + W4 + P24) { src = p2w; dst = p2h;  off = i - X4 - MEM4 - W4; bf = false; }
    else                               { src = p1w; dst = p1h;  off = i - X4 - MEM4 - W4 - P24; bf = false; }
    float4 v = ((const float4*)src)[off];
    ushort4 o;
    if (bf) { o.x = f2bf(v.x); o.y = f2bf(v.y); o.z = f2bf(v.z); o.w = f2bf(v.w); }
    else    { o.x = f2h(v.x);  o.y = f2h(v.y);  o.z = f2h(v.z);  o.w = f2h(v.w); }
    ((ushort4*)dst)[off] = o;
}

// ---------------------------------------------------------------------------
// K1: merged MFMA GEMM (bf16 in, f16 out) — exact R8 body.
// blocks [0,192): xh = x @ Wx^T + fc_b ; blocks [192,228): mh = mem @ Wm^T
// 64x128 tile, BK=32, 4 waves (2x2 of 32x64), register prefetch.
// ---------------------------------------------------------------------------
__global__ __launch_bounds__(256) void gemm_all(
    const ushort* __restrict__ xbf, const ushort* __restrict__ membf,
    const ushort* __restrict__ wbf, const float* __restrict__ fc_b,
    ushort* __restrict__ xh, ushort* __restrict__ mh)
{
    __shared__ ushort As[64 * ASTR];
    __shared__ ushort Bs[128 * ASTR];
    const int id = blockIdx.x;
    const int t  = threadIdx.x;

    const ushort* A; ushort* Out; int M, m0, n0, koff; bool xblk;
    if (id < 192) {
        xblk = true;  A = xbf;   Out = xh; M = B_;
        m0 = (id & 15) * 64; n0 = (id >> 4) * 128; koff = 0;
    } else {
        int q = id - 192;
        xblk = false; A = membf; Out = mh; M = C_;
        m0 = (q % 3) * 64; n0 = (q / 3) * 128; koff = D_;
    }

    const int wave = t >> 6, lane = t & 63;
    const int wm = (wave & 1) * 32, wn = (wave >> 1) * 64;
    const int fm = lane & 15, quad = lane >> 4;

    const int row_a = t >> 2, qa = (t & 3) * 8;
    const int ar = min(m0 + row_a, M - 1);
    const ushort* Arow = A + (size_t)ar * D_ + qa;
    const ushort* Brow = wbf + (size_t)(n0 + row_a) * TWOD + koff + qa;

    f32x4 acc[2][4];
#pragma unroll
    for (int j = 0; j < 4; ++j) {
        float bv = xblk ? fc_b[n0 + wn + j * 16 + fm] : 0.f;
#pragma unroll
        for (int i = 0; i < 2; ++i)
            acc[i][j] = (f32x4){bv, bv, bv, bv};
    }

    uint4 pa  = *(const uint4*)(Arow);
    uint4 pb0 = *(const uint4*)(Brow);
    uint4 pb1 = *(const uint4*)(Brow + 64 * TWOD);

    for (int k0 = 0; k0 < D_; k0 += 32) {
        __syncthreads();
        *(uint4*)&As[row_a * ASTR + qa] = pa;
        *(uint4*)&Bs[row_a * ASTR + qa] = pb0;
        *(uint4*)&Bs[(64 + row_a) * ASTR + qa] = pb1;
        __syncthreads();
        if (k0 + 32 < D_) {
            pa  = *(const uint4*)(Arow + k0 + 32);
            pb0 = *(const uint4*)(Brow + k0 + 32);
            pb1 = *(const uint4*)(Brow + 64 * TWOD + k0 + 32);
        }
        bfx8 af[2], bf[4];
#pragma unroll
        for (int i = 0; i < 2; ++i)
            af[i] = *(const bfx8*)&As[(wm + i * 16 + fm) * ASTR + quad * 8];
#pragma unroll
        for (int j = 0; j < 4; ++j)
            bf[j] = *(const bfx8*)&Bs[(wn + j * 16 + fm) * ASTR + quad * 8];
#pragma unroll
        for (int i = 0; i < 2; ++i)
#pragma unroll
            for (int j = 0; j < 4; ++j)
                acc[i][j] = __builtin_amdgcn_mfma_f32_16x16x32_bf16(
                    af[i], bf[j], acc[i][j], 0, 0, 0);
    }

#pragma unroll
    for (int i = 0; i < 2; ++i)
#pragma unroll
        for (int j = 0; j < 4; ++j)
#pragma unroll
            for (int r = 0; r < 4; ++r) {
                int row = m0 + wm + i * 16 + quad * 4 + r;
                int col = n0 + wn + j * 16 + fm;
                if (row < M) Out[(size_t)row * TWOD + col] = f2h(acc[i][j][r]);
            }
}

// ---------------------------------------------------------------------------
// K2: fused tile (f16) — exact R8 body.
// y<3: elementwise partial[z][b][c] = sum relu(xh+m)*p1 (pk_f16 + dot2).
// y==3: MFMA f16 u-projection partial[z][b][192+n] = sum relu(xh)*p2.
// ---------------------------------------------------------------------------
__global__ __launch_bounds__(256) void fused_tile(
    const ushort* __restrict__ xh, const ushort* __restrict__ mh,
    const ushort* __restrict__ p1h, const ushort* __restrict__ p2h,
    float* __restrict__ partial)
{
    __shared__ __align__(16) char smem[46080];
    const int t  = threadIdx.x;
    const int b0 = blockIdx.x * 128;
    const int z  = blockIdx.z;
    const int e0 = z * ECHUNK;

    if (blockIdx.y == 3) {
        ushort* Au = (ushort*)smem;                 // 128 x USTRU halves
        ushort* Wu = (ushort*)(smem + 30720);       // 64 x USTRU halves
        const int wave = t >> 6, lane = t & 63;
        const int fm = lane & 15, quad = lane >> 4;

        {   // stage relu(xh) f16 : 128 rows x 96 k
            const int row = t >> 1, kh = (t & 1) * 48;
            const ushort* src = xh + (size_t)(b0 + row) * TWOD + e0 + kh;
            uint4 v[6];
#pragma unroll
            for (int i = 0; i < 6; ++i) v[i] = *(const uint4*)&src[i * 8];
#pragma unroll
            for (int i = 0; i < 6; ++i) {
                v[i].x = relu2(v[i].x); v[i].y = relu2(v[i].y);
                v[i].z = relu2(v[i].z); v[i].w = relu2(v[i].w);
                *(uint4*)&Au[row * USTRU + kh + i * 8] = v[i];
            }
        }
        {   // stage p2 f16 : 64 rows x 96 k
            const int row = t >> 2, ks = (t & 3) * 24;
            const ushort* pw = p2h + (size_t)row * TWOD + e0 + ks;
#pragma unroll
            for (int i = 0; i < 3; ++i)
                *(uint4*)&Wu[row * USTRU + ks + i * 8] = *(const uint4*)&pw[i * 8];
        }
        __syncthreads();

        f32x4 uacc[2][4];
#pragma unroll
        for (int i = 0; i < 2; ++i)
#pragma unroll
            for (int j = 0; j < 4; ++j) uacc[i][j] = (f32x4){0.f, 0.f, 0.f, 0.f};
#pragma unroll
        for (int k0 = 0; k0 < ECHUNK; k0 += 32) {
            fp16x8 af[2], bf[4];
#pragma unroll
            for (int i = 0; i < 2; ++i)
                af[i] = *(const fp16x8*)&Au[(wave * 32 + i * 16 + fm) * USTRU + k0 + quad * 8];
#pragma unroll
            for (int j = 0; j < 4; ++j)
                bf[j] = *(const fp16x8*)&Wu[(j * 16 + fm) * USTRU + k0 + quad * 8];
#pragma unroll
            for (int i = 0; i < 2; ++i)
#pragma unroll
                for (int j = 0; j < 4; ++j)
                    uacc[i][j] = __builtin_amdgcn_mfma_f32_16x16x32_f16(
                        af[i], bf[j], uacc[i][j], 0, 0, 0);
        }
#pragma unroll
        for (int i = 0; i < 2; ++i)
#pragma unroll
            for (int j = 0; j < 4; ++j)
#pragma unroll
                for (int r = 0; r < 4; ++r) {
                    int row = b0 + wave * 32 + i * 16 + quad * 4 + r;
                    partial[((size_t)z * B_ + row) * CPAD + 192 + j * 16 + fm] =
                        uacc[i][j][r];
                }
        return;
    }

    // -------- elementwise f16 path: cols c0..c0+63 (c0 in {0,64,128}) -----
    unsigned* xT = (unsigned*)smem;             // [48 e-pairs][128 b]
    unsigned* mT = (unsigned*)(smem + 24576);   // [48][64 c]
    unsigned* wT = (unsigned*)(smem + 36864);   // [48]
    const int c0 = blockIdx.y * 64;
    const int tm = t & 15, tn = t >> 4;

    {   // stage x: 2 thr/row, 48 halves each
        const int row = t >> 1, ph = (t & 1) * 48;
        const ushort* src = xh + (size_t)(b0 + row) * TWOD + e0 + ph;
        uint4 v[6];
#pragma unroll
        for (int i = 0; i < 6; ++i) v[i] = *(const uint4*)&src[i * 8];
#pragma unroll
        for (int i = 0; i < 6; ++i) {
            const int ep = (t & 1) * 24 + i * 4;
            xT[(ep + 0) * 128 + row] = v[i].x;
            xT[(ep + 1) * 128 + row] = v[i].y;
            xT[(ep + 2) * 128 + row] = v[i].z;
            xT[(ep + 3) * 128 + row] = v[i].w;
        }
    }
    {   // stage m: 4 thr/col, 24 halves each
        const int col = t & 63, seg = t >> 6;
        const int gc  = c0 + col;
        uint4 v[3];
        if (gc < C_) {
            const ushort* src = mh + (size_t)gc * TWOD + e0 + seg * 24;
#pragma unroll
            for (int i = 0; i < 3; ++i) v[i] = *(const uint4*)&src[i * 8];
        } else {
#pragma unroll
            for (int i = 0; i < 3; ++i) v[i] = make_uint4(0, 0, 0, 0);
        }
#pragma unroll
        for (int i = 0; i < 3; ++i) {
            const int ep = seg * 12 + i * 4;
            mT[(ep + 0) * 64 + col] = v[i].x;
            mT[(ep + 1) * 64 + col] = v[i].y;
            mT[(ep + 2) * 64 + col] = v[i].z;
            mT[(ep + 3) * 64 + col] = v[i].w;
        }
    }
    if (t < 12) {  // stage w (p1): 96 halves
        uint4 v = *(const uint4*)&p1h[e0 + t * 8];
        wT[t * 4 + 0] = v.x; wT[t * 4 + 1] = v.y;
        wT[t * 4 + 2] = v.z; wT[t * 4 + 3] = v.w;
    }
    __syncthreads();

    float acc[8][4] = {};
#pragma unroll 4
    for (int ep = 0; ep < 48; ++ep) {
        uint4 a0 = *(const uint4*)&xT[ep * 128 + tm * 8];
        uint4 a1 = *(const uint4*)&xT[ep * 128 + tm * 8 + 4];
        uint4 mj = *(const uint4*)&mT[ep * 64 + tn * 4];
        const unsigned wv = wT[ep];
        const unsigned aa[8] = {a0.x, a0.y, a0.z, a0.w, a1.x, a1.y, a1.z, a1.w};
        const unsigned mm[4] = {mj.x, mj.y, mj.z, mj.w};
#pragma unroll
        for (int i = 0; i < 8; ++i)
#pragma unroll
            for (int j = 0; j < 4; ++j)
                acc[i][j] = dot2acc(addrelu2(aa[i], mm[j]), wv, acc[i][j]);
    }

#pragma unroll
    for (int i = 0; i < 8; ++i) {
        const int gb = b0 + tm * 8 + i;
        float4 v = make_float4(acc[i][0], acc[i][1], acc[i][2], acc[i][3]);
        *(float4*)&partial[((size_t)z * B_ + gb) * CPAD + c0 + tn * 4] = v;
    }
}

// ---------------------------------------------------------------------------
// K3: per-row reduce of partials + bias, u-normalize (-> f16) + cls loss.
// ---------------------------------------------------------------------------
__global__ __launch_bounds__(256) void reduce_row(
    const float* __restrict__ partial,
    const float* __restrict__ p1b, const float* __restrict__ p2b,
    const int* __restrict__ lb,
    ushort* __restrict__ uhf, float* __restrict__ sqn,
    float* __restrict__ clsbuf)
{
    const int b = blockIdx.x, t = threadIdx.x;
    float v = 0.f;
#pragma unroll
    for (int z = 0; z < ECHUNKS; ++z)
        v += partial[((size_t)z * B_ + b) * CPAD + t];
    if (t < NCLS)       v += p1b[0];
    else if (t >= 192)  v += p2b[t - 192];

    __shared__ float sval[256];
    sval[t] = v;
    __syncthreads();

    if (t < 64) {
        float uv = sval[192 + t];
        float s = uv * uv;
#pragma unroll
        for (int off = 32; off; off >>= 1) s += __shfl_xor(s, off);
        float inv = 1.f / fmaxf(sqrtf(s), 1e-12f);
        uhf[(size_t)b * P_ + t] = f2h(uv * inv);
        if (t == 0) sqn[b] = s * inv * inv;

        const int l = lb[b];
        float mx = -1e30f;
        for (int j = t; j < NCLS; j += 64)
            if (!(j == l && l < C_)) mx = fmaxf(mx, sval[j]);
#pragma unroll
        for (int off = 32; off; off >>= 1) mx = fmaxf(mx, __shfl_xor(mx, off));
        float se = 0.f;
        for (int j = t; j < NCLS; j += 64)
            if (!(j == l && l < C_)) se += expf(sval[j] - mx);
#pragma unroll
        for (int off = 32; off; off >>= 1) se += __shfl_xor(se, off);

        if (t == 0) {
            float l150  = sval[C_];
            float loss2 = mx + logf(se) - l150;
            float loss1 = 0.f;
            if (l < C_) {
                float a  = sval[l];
                float m2 = fmaxf(a, l150);
                loss1 = m2 - a + logf(expf(a - m2) + expf(l150 - m2));
            }
            clsbuf[b] = loss1 + loss2;
        }
    }
}

// ---------------------------------------------------------------------------
// K4: pairwise margin losses (f16 MFMA Gram) + last-block-done finalize.
// Grid flat 256 blocks (16x16 pair tiles). R11-validated.
// ---------------------------------------------------------------------------
__global__ __launch_bounds__(256) void pair_loss(
    const ushort* __restrict__ uhf, const float* __restrict__ sqn,
    const int* __restrict__ lb, const float* __restrict__ clsbuf,
    float* __restrict__ pairpart, int* __restrict__ ctr,
    float* __restrict__ out)
{
    __shared__ ushort ui_s[64 * USTR];
    __shared__ ushort uj_s[64 * USTR];
    __shared__ float sni[64], snj[64];
    __shared__ int   li[64],  lj[64];
    __shared__ float red[5][4];
    __shared__ int   isLast;

    const int t  = threadIdx.x;
    const int id = blockIdx.x;
    const int i0 = (id & 15) * 64, j0 = (id >> 4) * 64;

    for (int idx = t; idx < 512; idx += 256) {
        int row = idx >> 3, ch = (idx & 7) * 8;
        *(uint4*)&ui_s[row * USTR + ch] =
            *(const uint4*)&uhf[(size_t)(i0 + row) * P_ + ch];
        *(uint4*)&uj_s[row * USTR + ch] =
            *(const uint4*)&uhf[(size_t)(j0 + row) * P_ + ch];
    }
    if (t < 64)       { sni[t] = sqn[i0 + t]; li[t] = lb[i0 + t]; }
    else if (t < 128) { int q = t - 64; snj[q] = sqn[j0 + q]; lj[q] = lb[j0 + q]; }
    __syncthreads();

    const int wave = t >> 6, lane = t & 63;
    const int n = lane & 15, quad = lane >> 4;
    const int iw = wave * 16;

    const fp16x8 af0 = *(const fp16x8*)&ui_s[(iw + n) * USTR + quad * 8];
    const fp16x8 af1 = *(const fp16x8*)&ui_s[(iw + n) * USTR + quad * 8 + 32];

    f32x4 acc[4];
#pragma unroll
    for (int jt = 0; jt < 4; ++jt) {
        const fp16x8 bf0 = *(const fp16x8*)&uj_s[(jt * 16 + n) * USTR + quad * 8];
        const fp16x8 bf1 = *(const fp16x8*)&uj_s[(jt * 16 + n) * USTR + quad * 8 + 32];
        acc[jt] = __builtin_amdgcn_mfma_f32_16x16x32_f16(
            af0, bf0, (f32x4){0.f, 0.f, 0.f, 0.f}, 0, 0, 0);
        acc[jt] = __builtin_amdgcn_mfma_f32_16x16x32_f16(
            af1, bf1, acc[jt], 0, 0, 0);
    }

    float ps = 0.f, pc = 0.f, ns = 0.f, nc = 0.f;
#pragma unroll
    for (int jt = 0; jt < 4; ++jt)
#pragma unroll
        for (int r = 0; r < 4; ++r) {
            const int il = iw + quad * 4 + r;
            const int jl = jt * 16 + n;
            float sq = sni[il] + snj[jl] - 2.f * acc[jt][r];
            float dist = sq > 0.f ? sqrtf(fmaxf(sq, 1e-16f)) : 0.f;
            bool same = (li[il] == lj[jl]);
            if (same) {
                if (i0 + il != j0 + jl) { ps += fmaxf(dist - 0.7f, 0.f); pc += 1.f; }
            } else {
                ns += fmaxf(1.4f - dist, 0.f); nc += 1.f;
            }
        }

#pragma unroll
    for (int off = 32; off; off >>= 1) {
        ps += __shfl_xor(ps, off); pc += __shfl_xor(pc, off);
        ns += __shfl_xor(ns, off); nc += __shfl_xor(nc, off);
    }
    if (lane == 0) { red[0][wave] = ps; red[1][wave] = pc;
                     red[2][wave] = ns; red[3][wave] = nc; }
    __syncthreads();
    if (t == 0) {
        float4 v;
        v.x = red[0][0] + red[0][1] + red[0][2] + red[0][3];
        v.y = red[1][0] + red[1][1] + red[1][2] + red[1][3];
        v.z = red[2][0] + red[2][1] + red[2][2] + red[2][3];
        v.w = red[3][0] + red[3][1] + red[3][2] + red[3][3];
        *(float4*)&pairpart[(size_t)id * 4] = v;
        __threadfence();                       // release our partial
        int old = atomicAdd(ctr, 1);
        isLast = (old == 255);
    }
    __syncthreads();

    if (isLast) {
        __threadfence();                       // acquire all partials
        float c = clsbuf[t] + clsbuf[t + 256] + clsbuf[t + 512] + clsbuf[t + 768];
        float4 pp = *(const float4*)&pairpart[(size_t)t * 4];
        float fps = pp.x, fpc = pp.y, fns = pp.z, fnc = pp.w;
#pragma unroll
        for (int off = 32; off; off >>= 1) {
            c   += __shfl_xor(c, off);
            fps += __shfl_xor(fps, off); fpc += __shfl_xor(fpc, off);
            fns += __shfl_xor(fns, off); fnc += __shfl_xor(fnc, off);
        }
        __syncthreads();   // red[] reuse
        if (lane == 0) { red[0][wave] = c;   red[1][wave] = fps;
                         red[2][wave] = fpc; red[3][wave] = fns;
                         red[4][wave] = fnc; }
        __syncthreads();
        if (t == 0) {
            float C = 0.f, PS = 0.f, PC = 0.f, NS = 0.f, NC = 0.f;
#pragma unroll
            for (int w = 0; w < 4; ++w) {
                C += red[0][w]; PS += red[1][w]; PC += red[2][w];
                NS += red[3][w]; NC += red[4][w];
            }
            out[0] = C / (float)B_ + PS / fmaxf(PC, 1.f) + NS / fmaxf(NC, 1.f);
        }
    }
}

extern "C" void kernel_launch(void* const* d_in, const int* in_sizes, int n_in,
                              void* d_out, int out_size, void* d_ws, size_t ws_size,
                              hipStream_t stream)
{
    const float* x    = (const float*)d_in[0];
    const int*   lb   = (const int*)d_in[1];
    const float* mem  = (const float*)d_in[2];
    const float* fc_w = (const float*)d_in[3];
    const float* fc_b = (const float*)d_in[4];
    const float* p1w  = (const float*)d_in[5];
    const float* p1b  = (const float*)d_in[6];
    const float* p2w  = (const float*)d_in[7];
    const float* p2b  = (const float*)d_in[8];

    float* ws       = (float*)d_ws;
    ushort* mh      = (ushort*)(ws + OFF_MH);
    ushort* xh      = (ushort*)(ws + OFF_XH);
    float* partials = ws + OFF_PARTIAL;
    ushort* uhf     = (ushort*)(ws + OFF_UHF);
    float* sqn      = ws + OFF_SQN;
    float* clsbuf   = ws + OFF_CLS;
    float* pairpart = ws + OFF_PAIR;
    int*   ctr      = (int*)(ws + OFF_CTR);
    ushort* xbf     = (ushort*)(ws + OFF_XBF);
    ushort* membf   = (ushort*)(ws + OFF_MEMBF);
    ushort* wbf     = (ushort*)(ws + OFF_WBF);
    ushort* p2h     = (ushort*)(ws + OFF_P2H);
    ushort* p1h     = (ushort*)(ws + OFF_P1H);

    // K0: dtype conversions + ctr zero
    prep_cvt<<<(TOT4 + 255) / 256, 256, 0, stream>>>(x, mem, fc_w, p2w, p1w,
                                                     xbf, membf, wbf, p2h, p1h,
                                                     ctr);
    // K1: merged gemms (bf16 in) -> f16 xh (bias folded), f16 mh
    gemm_all<<<228, 256, 0, stream>>>(xbf, membf, wbf, fc_b, xh, mh);
    // K2: fused elementwise logits partials (f16 dot2) + MFMA f16 u-partials
    fused_tile<<<dim3(8, 4, ECHUNKS), 256, 0, stream>>>(xh, mh, p1h, p2h,
                                                        partials);
    // K3: reduce partials + bias, normalize u (f16), classification loss
    reduce_row<<<B_, 256, 0, stream>>>(partials, p1b, p2b, lb, uhf, sqn, clsbuf);
    // K4: pairwise margin losses + last-block finalize
    pair_loss<<<256, 256, 0, stream>>>(uhf, sqn, lb, clsbuf, pairpart, ctr,
                                       (float*)d_out);
}

// Round 13
// 136.739 us; speedup vs baseline: 2.9536x; 1.0085x over previous
//
#include <hip/hip_runtime.h>
#include <math.h>

// Problem constants
#define B_    1024
#define D_    768
#define C_    150
#define P_    64
#define TWOD  1536
#define NCLS  151   // C+1
#define CPAD  256   // partial row: 0..150 logits, 151..191 junk, 192..255 u

// fused_tile: 128b x 64c per block, 8x4/thr, e split 16 ways (R8-proven)
#define ECHUNKS 16
#define ECHUNK  96

#define ASTR  40    // gemm LDS stride (bf16)
#define USTRU 120   // u-path LDS stride (halves)
#define USTR  72    // pair_loss LDS stride (halves)

// Workspace layout (float offsets)
#define OFF_MH      0                                   // half[150*1536]
#define OFF_XH      (OFF_MH + (C_ * TWOD) / 2)          // half[1024*1536]
#define OFF_PARTIAL (OFF_XH + (B_ * TWOD) / 2)          // fp32[16*1024*256]
#define OFF_UHF     (OFF_PARTIAL + ECHUNKS * B_ * CPAD) // half[1024*64]
#define OFF_SQN     (OFF_UHF + (B_ * P_) / 2)
#define OFF_CLS     (OFF_SQN + B_)
#define OFF_PAIR    (OFF_CLS + B_)
#define OFF_CTR     (OFF_PAIR + 1024)
#define OFF_XBF     (OFF_CTR + 4)
#define OFF_MEMBF   (OFF_XBF + (B_ * D_) / 2)
#define OFF_WBF     (OFF_MEMBF + (C_ * D_) / 2)
#define OFF_P2H     (OFF_WBF + (TWOD * TWOD) / 2)
#define OFF_P1H     (OFF_P2H + (P_ * TWOD) / 2)
// end ~6.82M floats ~ 27.3 MB

typedef __bf16    bfx8   __attribute__((ext_vector_type(8)));
typedef _Float16  fp16x8 __attribute__((ext_vector_type(8)));
typedef _Float16  h2v    __attribute__((ext_vector_type(2)));
typedef float     f32x4  __attribute__((ext_vector_type(4)));

__device__ inline ushort f2bf(float f) {
    union { float f; unsigned u; } c; c.f = f;
    unsigned r = c.u + 0x7fffu + ((c.u >> 16) & 1u);
    return (ushort)(r >> 16);
}
__device__ inline ushort f2h(float f) {
    _Float16 h = (_Float16)f;
    return __builtin_bit_cast(ushort, h);
}
__device__ inline unsigned addrelu2(unsigned a, unsigned m) {
    h2v s = __builtin_bit_cast(h2v, a) + __builtin_bit_cast(h2v, m);
    h2v z = {(_Float16)0.f, (_Float16)0.f};
    s = __builtin_elementwise_max(s, z);
    return __builtin_bit_cast(unsigned, s);
}
__device__ inline unsigned relu2(unsigned a) {
    h2v s = __builtin_bit_cast(h2v, a);
    h2v z = {(_Float16)0.f, (_Float16)0.f};
    s = __builtin_elementwise_max(s, z);
    return __builtin_bit_cast(unsigned, s);
}
__device__ inline float dot2acc(unsigned a, unsigned b, float c) {
    return __builtin_amdgcn_fdot2(__builtin_bit_cast(h2v, a),
                                  __builtin_bit_cast(h2v, b), c, false);
}

// ---------------------------------------------------------------------------
// K0: fp32 -> bf16 (x, mem, fc_w) and fp32 -> f16 (p2w, p1w); zero ctr.
// ---------------------------------------------------------------------------
#define X4   (B_ * D_ / 4)
#define MEM4 (C_ * D_ / 4)
#define W4   (TWOD * TWOD / 4)
#define P24  (P_ * TWOD / 4)
#define P14  (TWOD / 4)
#define TOT4 (X4 + MEM4 + W4 + P24 + P14)

__global__ __launch_bounds__(256) void prep_cvt(
    const float* __restrict__ x, const float* __restrict__ mem,
    const float* __restrict__ w, const float* __restrict__ p2w,
    const float* __restrict__ p1w,
    ushort* __restrict__ xb, ushort* __restrict__ memb,
    ushort* __restrict__ wb, ushort* __restrict__ p2h,
    ushort* __restrict__ p1h, int* __restrict__ ctr)
{
    int i = blockIdx.x * 256 + threadIdx.x;
    if (i == 0) *ctr = 0;
    if (i >= TOT4) return;
    const float* src; ushort* dst; int off; bool bf;
    if (i < X4)                        { src = x;   dst = xb;   off = i; bf = true; }
    else if (i < X4 + MEM4)            { src = mem; dst = memb; off = i - X4; bf = true; }
    else if (i < X4 + MEM4 + W4)       { src = w;   dst = wb;   off = i - X4 - MEM4; bf = true; }
    else if (i < X4 + MEM4 + W4 + P24) { src = p2w; dst = p2h;  off = i - X4 - MEM4 - W4; bf = false; }
    else                               { src = p1w; dst = p1h;  off = i - X4 - MEM4 - W4 - P24; bf = false; }
    float4 v = ((const float4*)src)[off];
    ushort4 o;
    if (bf) { o.x = f2bf(v.x); o.y = f2bf(v.y); o.z = f2bf(v.z); o.w = f2bf(v.w); }
    else    { o.x = f2h(v.x);  o.y = f2h(v.y);  o.z = f2h(v.z);  o.w = f2h(v.w); }
    ((ushort4*)dst)[off] = o;
}

// ---------------------------------------------------------------------------
// K1: merged MFMA GEMM (bf16 in, f16 out), 64x64 tiles for ~2 blocks/CU.
// blocks [0,384): xh = x @ Wx^T + fc_b ; blocks [384,456): mh = mem @ Wm^T
// BK=32, 4 waves (2x2 of 32x32), register prefetch.
// ---------------------------------------------------------------------------
__global__ __launch_bounds__(256) void gemm_all(
    const ushort* __restrict__ xbf, const ushort* __restrict__ membf,
    const ushort* __restrict__ wbf, const float* __restrict__ fc_b,
    ushort* __restrict__ xh, ushort* __restrict__ mh)
{
    __shared__ ushort As[64 * ASTR];
    __shared__ ushort Bs[64 * ASTR];
    const int id = blockIdx.x;
    const int t  = threadIdx.x;

    const ushort* A; ushort* Out; int M, m0, n0, koff; bool xblk;
    if (id < 384) {
        xblk = true;  A = xbf;   Out = xh; M = B_;
        m0 = (id & 15) * 64; n0 = (id >> 4) * 64; koff = 0;
    } else {
        int q = id - 384;
        xblk = false; A = membf; Out = mh; M = C_;
        m0 = (q % 3) * 64; n0 = (q / 3) * 64; koff = D_;
    }

    const int wave = t >> 6, lane = t & 63;
    const int wm = (wave & 1) * 32, wn = (wave >> 1) * 32;
    const int fm = lane & 15, quad = lane >> 4;

    const int row_a = t >> 2, qa = (t & 3) * 8;
    const int ar = min(m0 + row_a, M - 1);
    const ushort* Arow = A + (size_t)ar * D_ + qa;
    const ushort* Brow = wbf + (size_t)(n0 + row_a) * TWOD + koff + qa;

    f32x4 acc[2][2];
#pragma unroll
    for (int j = 0; j < 2; ++j) {
        float bv = xblk ? fc_b[n0 + wn + j * 16 + fm] : 0.f;
#pragma unroll
        for (int i = 0; i < 2; ++i)
            acc[i][j] = (f32x4){bv, bv, bv, bv};
    }

    uint4 pa = *(const uint4*)(Arow);
    uint4 pb = *(const uint4*)(Brow);

    for (int k0 = 0; k0 < D_; k0 += 32) {
        __syncthreads();   // prev frag reads done
        *(uint4*)&As[row_a * ASTR + qa] = pa;
        *(uint4*)&Bs[row_a * ASTR + qa] = pb;
        __syncthreads();
        if (k0 + 32 < D_) {
            pa = *(const uint4*)(Arow + k0 + 32);
            pb = *(const uint4*)(Brow + k0 + 32);
        }
        bfx8 af[2], bf[2];
#pragma unroll
        for (int i = 0; i < 2; ++i) {
            af[i] = *(const bfx8*)&As[(wm + i * 16 + fm) * ASTR + quad * 8];
            bf[i] = *(const bfx8*)&Bs[(wn + i * 16 + fm) * ASTR + quad * 8];
        }
#pragma unroll
        for (int i = 0; i < 2; ++i)
#pragma unroll
            for (int j = 0; j < 2; ++j)
                acc[i][j] = __builtin_amdgcn_mfma_f32_16x16x32_bf16(
                    af[i], bf[j], acc[i][j], 0, 0, 0);
    }

#pragma unroll
    for (int i = 0; i < 2; ++i)
#pragma unroll
        for (int j = 0; j < 2; ++j)
#pragma unroll
            for (int r = 0; r < 4; ++r) {
                int row = m0 + wm + i * 16 + quad * 4 + r;
                int col = n0 + wn + j * 16 + fm;
                if (row < M) Out[(size_t)row * TWOD + col] = f2h(acc[i][j][r]);
            }
}

// ---------------------------------------------------------------------------
// K2: fused tile (f16) — exact R8 body.
// y<3: elementwise partial[z][b][c] = sum relu(xh+m)*p1 (pk_f16 + dot2).
// y==3: MFMA f16 u-projection partial[z][b][192+n] = sum relu(xh)*p2.
// ---------------------------------------------------------------------------
__global__ __launch_bounds__(256) void fused_tile(
    const ushort* __restrict__ xh, const ushort* __restrict__ mh,
    const ushort* __restrict__ p1h, const ushort* __restrict__ p2h,
    float* __restrict__ partial)
{
    __shared__ __align__(16) char smem[46080];
    const int t  = threadIdx.x;
    const int b0 = blockIdx.x * 128;
    const int z  = blockIdx.z;
    const int e0 = z * ECHUNK;

    if (blockIdx.y == 3) {
        ushort* Au = (ushort*)smem;                 // 128 x USTRU halves
        ushort* Wu = (ushort*)(smem + 30720);       // 64 x USTRU halves
        const int wave = t >> 6, lane = t & 63;
        const int fm = lane & 15, quad = lane >> 4;

        {   // stage relu(xh) f16 : 128 rows x 96 k
            const int row = t >> 1, kh = (t & 1) * 48;
            const ushort* src = xh + (size_t)(b0 + row) * TWOD + e0 + kh;
            uint4 v[6];
#pragma unroll
            for (int i = 0; i < 6; ++i) v[i] = *(const uint4*)&src[i * 8];
#pragma unroll
            for (int i = 0; i < 6; ++i) {
                v[i].x = relu2(v[i].x); v[i].y = relu2(v[i].y);
                v[i].z = relu2(v[i].z); v[i].w = relu2(v[i].w);
                *(uint4*)&Au[row * USTRU + kh + i * 8] = v[i];
            }
        }
        {   // stage p2 f16 : 64 rows x 96 k
            const int row = t >> 2, ks = (t & 3) * 24;
            const ushort* pw = p2h + (size_t)row * TWOD + e0 + ks;
#pragma unroll
            for (int i = 0; i < 3; ++i)
                *(uint4*)&Wu[row * USTRU + ks + i * 8] = *(const uint4*)&pw[i * 8];
        }
        __syncthreads();

        f32x4 uacc[2][4];
#pragma unroll
        for (int i = 0; i < 2; ++i)
#pragma unroll
            for (int j = 0; j < 4; ++j) uacc[i][j] = (f32x4){0.f, 0.f, 0.f, 0.f};
#pragma unroll
        for (int k0 = 0; k0 < ECHUNK; k0 += 32) {
            fp16x8 af[2], bf[4];
#pragma unroll
            for (int i = 0; i < 2; ++i)
                af[i] = *(const fp16x8*)&Au[(wave * 32 + i * 16 + fm) * USTRU + k0 + quad * 8];
#pragma unroll
            for (int j = 0; j < 4; ++j)
                bf[j] = *(const fp16x8*)&Wu[(j * 16 + fm) * USTRU + k0 + quad * 8];
#pragma unroll
            for (int i = 0; i < 2; ++i)
#pragma unroll
                for (int j = 0; j < 4; ++j)
                    uacc[i][j] = __builtin_amdgcn_mfma_f32_16x16x32_f16(
                        af[i], bf[j], uacc[i][j], 0, 0, 0);
        }
#pragma unroll
        for (int i = 0; i < 2; ++i)
#pragma unroll
            for (int j = 0; j < 4; ++j)
#pragma unroll
                for (int r = 0; r < 4; ++r) {
                    int row = b0 + wave * 32 + i * 16 + quad * 4 + r;
                    partial[((size_t)z * B_ + row) * CPAD + 192 + j * 16 + fm] =
                        uacc[i][j][r];
                }
        return;
    }

    // -------- elementwise f16 path: cols c0..c0+63 (c0 in {0,64,128}) -----
    unsigned* xT = (unsigned*)smem;             // [48 e-pairs][128 b]
    unsigned* mT = (unsigned*)(smem + 24576);   // [48][64 c]
    unsigned* wT = (unsigned*)(smem + 36864);   // [48]
    const int c0 = blockIdx.y * 64;
    const int tm = t & 15, tn = t >> 4;

    {   // stage x: 2 thr/row, 48 halves each
        const int row = t >> 1, ph = (t & 1) * 48;
        const ushort* src = xh + (size_t)(b0 + row) * TWOD + e0 + ph;
        uint4 v[6];
#pragma unroll
        for (int i = 0; i < 6; ++i) v[i] = *(const uint4*)&src[i * 8];
#pragma unroll
        for (int i = 0; i < 6; ++i) {
            const int ep = (t & 1) * 24 + i * 4;
            xT[(ep + 0) * 128 + row] = v[i].x;
            xT[(ep + 1) * 128 + row] = v[i].y;
            xT[(ep + 2) * 128 + row] = v[i].z;
            xT[(ep + 3) * 128 + row] = v[i].w;
        }
    }
    {   // stage m: 4 thr/col, 24 halves each
        const int col = t & 63, seg = t >> 6;
        const int gc  = c0 + col;
        uint4 v[3];
        if (gc < C_) {
            const ushort* src = mh + (size_t)gc * TWOD + e0 + seg * 24;
#pragma unroll
            for (int i = 0; i < 3; ++i) v[i] = *(const uint4*)&src[i * 8];
        } else {
#pragma unroll
            for (int i = 0; i < 3; ++i) v[i] = make_uint4(0, 0, 0, 0);
        }
#pragma unroll
        for (int i = 0; i < 3; ++i) {
            const int ep = seg * 12 + i * 4;
            mT[(ep + 0) * 64 + col] = v[i].x;
            mT[(ep + 1) * 64 + col] = v[i].y;
            mT[(ep + 2) * 64 + col] = v[i].z;
            mT[(ep + 3) * 64 + col] = v[i].w;
        }
    }
    if (t < 12) {  // stage w (p1): 96 halves
        uint4 v = *(const uint4*)&p1h[e0 + t * 8];
        wT[t * 4 + 0] = v.x; wT[t * 4 + 1] = v.y;
        wT[t * 4 + 2] = v.z; wT[t * 4 + 3] = v.w;
    }
    __syncthreads();

    float acc[8][4] = {};
#pragma unroll 4
    for (int ep = 0; ep < 48; ++ep) {
        uint4 a0 = *(const uint4*)&xT[ep * 128 + tm * 8];
        uint4 a1 = *(const uint4*)&xT[ep * 128 + tm * 8 + 4];
        uint4 mj = *(const uint4*)&mT[ep * 64 + tn * 4];
        const unsigned wv = wT[ep];
        const unsigned aa[8] = {a0.x, a0.y, a0.z, a0.w, a1.x, a1.y, a1.z, a1.w};
        const unsigned mm[4] = {mj.x, mj.y, mj.z, mj.w};
#pragma unroll
        for (int i = 0; i < 8; ++i)
#pragma unroll
            for (int j = 0; j < 4; ++j)
                acc[i][j] = dot2acc(addrelu2(aa[i], mm[j]), wv, acc[i][j]);
    }

#pragma unroll
    for (int i = 0; i < 8; ++i) {
        const int gb = b0 + tm * 8 + i;
        float4 v = make_float4(acc[i][0], acc[i][1], acc[i][2], acc[i][3]);
        *(float4*)&partial[((size_t)z * B_ + gb) * CPAD + c0 + tn * 4] = v;
    }
}

// ---------------------------------------------------------------------------
// K3: per-row reduce of partials + bias, u-normalize (-> f16) + cls loss.
// ---------------------------------------------------------------------------
__global__ __launch_bounds__(256) void reduce_row(
    const float* __restrict__ partial,
    const float* __restrict__ p1b, const float* __restrict__ p2b,
    const int* __restrict__ lb,
    ushort* __restrict__ uhf, float* __restrict__ sqn,
    float* __restrict__ clsbuf)
{
    const int b = blockIdx.x, t = threadIdx.x;
    float v = 0.f;
#pragma unroll
    for (int z = 0; z < ECHUNKS; ++z)
        v += partial[((size_t)z * B_ + b) * CPAD + t];
    if (t < NCLS)       v += p1b[0];
    else if (t >= 192)  v += p2b[t - 192];

    __shared__ float sval[256];
    sval[t] = v;
    __syncthreads();

    if (t < 64) {
        float uv = sval[192 + t];
        float s = uv * uv;
#pragma unroll
        for (int off = 32; off; off >>= 1) s += __shfl_xor(s, off);
        float inv = 1.f / fmaxf(sqrtf(s), 1e-12f);
        uhf[(size_t)b * P_ + t] = f2h(uv * inv);
        if (t == 0) sqn[b] = s * inv * inv;

        const int l = lb[b];
        float mx = -1e30f;
        for (int j = t; j < NCLS; j += 64)
            if (!(j == l && l < C_)) mx = fmaxf(mx, sval[j]);
#pragma unroll
        for (int off = 32; off; off >>= 1) mx = fmaxf(mx, __shfl_xor(mx, off));
        float se = 0.f;
        for (int j = t; j < NCLS; j += 64)
            if (!(j == l && l < C_)) se += expf(sval[j] - mx);
#pragma unroll
        for (int off = 32; off; off >>= 1) se += __shfl_xor(se, off);

        if (t == 0) {
            float l150  = sval[C_];
            float loss2 = mx + logf(se) - l150;
            float loss1 = 0.f;
            if (l < C_) {
                float a  = sval[l];
                float m2 = fmaxf(a, l150);
                loss1 = m2 - a + logf(expf(a - m2) + expf(l150 - m2));
            }
            clsbuf[b] = loss1 + loss2;
        }
    }
}

// ---------------------------------------------------------------------------
// K4: pairwise margin losses (f16 MFMA Gram) + last-block-done finalize.
// Grid flat 256 blocks (16x16 pair tiles). R11/R12-validated.
// ---------------------------------------------------------------------------
__global__ __launch_bounds__(256) void pair_loss(
    const ushort* __restrict__ uhf, const float* __restrict__ sqn,
    const int* __restrict__ lb, const float* __restrict__ clsbuf,
    float* __restrict__ pairpart, int* __restrict__ ctr,
    float* __restrict__ out)
{
    __shared__ ushort ui_s[64 * USTR];
    __shared__ ushort uj_s[64 * USTR];
    __shared__ float sni[64], snj[64];
    __shared__ int   li[64],  lj[64];
    __shared__ float red[5][4];
    __shared__ int   isLast;

    const int t  = threadIdx.x;
    const int id = blockIdx.x;
    const int i0 = (id & 15) * 64, j0 = (id >> 4) * 64;

    for (int idx = t; idx < 512; idx += 256) {
        int row = idx >> 3, ch = (idx & 7) * 8;
        *(uint4*)&ui_s[row * USTR + ch] =
            *(const uint4*)&uhf[(size_t)(i0 + row) * P_ + ch];
        *(uint4*)&uj_s[row * USTR + ch] =
            *(const uint4*)&uhf[(size_t)(j0 + row) * P_ + ch];
    }
    if (t < 64)       { sni[t] = sqn[i0 + t]; li[t] = lb[i0 + t]; }
    else if (t < 128) { int q = t - 64; snj[q] = sqn[j0 + q]; lj[q] = lb[j0 + q]; }
    __syncthreads();

    const int wave = t >> 6, lane = t & 63;
    const int n = lane & 15, quad = lane >> 4;
    const int iw = wave * 16;

    const fp16x8 af0 = *(const fp16x8*)&ui_s[(iw + n) * USTR + quad * 8];
    const fp16x8 af1 = *(const fp16x8*)&ui_s[(iw + n) * USTR + quad * 8 + 32];

    f32x4 acc[4];
#pragma unroll
    for (int jt = 0; jt < 4; ++jt) {
        const fp16x8 bf0 = *(const fp16x8*)&uj_s[(jt * 16 + n) * USTR + quad * 8];
        const fp16x8 bf1 = *(const fp16x8*)&uj_s[(jt * 16 + n) * USTR + quad * 8 + 32];
        acc[jt] = __builtin_amdgcn_mfma_f32_16x16x32_f16(
            af0, bf0, (f32x4){0.f, 0.f, 0.f, 0.f}, 0, 0, 0);
        acc[jt] = __builtin_amdgcn_mfma_f32_16x16x32_f16(
            af1, bf1, acc[jt], 0, 0, 0);
    }

    float ps = 0.f, pc = 0.f, ns = 0.f, nc = 0.f;
#pragma unroll
    for (int jt = 0; jt < 4; ++jt)
#pragma unroll
        for (int r = 0; r < 4; ++r) {
            const int il = iw + quad * 4 + r;
            const int jl = jt * 16 + n;
            float sq = sni[il] + snj[jl] - 2.f * acc[jt][r];
            float dist = sq > 0.f ? sqrtf(fmaxf(sq, 1e-16f)) : 0.f;
            bool same = (li[il] == lj[jl]);
            if (same) {
                if (i0 + il != j0 + jl) { ps += fmaxf(dist - 0.7f, 0.f); pc += 1.f; }
            } else {
                ns += fmaxf(1.4f - dist, 0.f); nc += 1.f;
            }
        }

#pragma unroll
    for (int off = 32; off; off >>= 1) {
        ps += __shfl_xor(ps, off); pc += __shfl_xor(pc, off);
        ns += __shfl_xor(ns, off); nc += __shfl_xor(nc, off);
    }
    if (lane == 0) { red[0][wave] = ps; red[1][wave] = pc;
                     red[2][wave] = ns; red[3][wave] = nc; }
    __syncthreads();
    if (t == 0) {
        float4 v;
        v.x = red[0][0] + red[0][1] + red[0][2] + red[0][3];
        v.y = red[1][0] + red[1][1] + red[1][2] + red[1][3];
        v.z = red[2][0] + red[2][1] + red[2][2] + red[2][3];
        v.w = red[3][0] + red[3][1] + red[3][2] + red[3][3];
        *(float4*)&pairpart[(size_t)id * 4] = v;
        __threadfence();                       // release our partial
        int old = atomicAdd(ctr, 1);
        isLast = (old == 255);
    }
    __syncthreads();

    if (isLast) {
        __threadfence();                       // acquire all partials
        float c = clsbuf[t] + clsbuf[t + 256] + clsbuf[t + 512] + clsbuf[t + 768];
        float4 pp = *(const float4*)&pairpart[(size_t)t * 4];
        float fps = pp.x, fpc = pp.y, fns = pp.z, fnc = pp.w;
#pragma unroll
        for (int off = 32; off; off >>= 1) {
            c   += __shfl_xor(c, off);
            fps += __shfl_xor(fps, off); fpc += __shfl_xor(fpc, off);
            fns += __shfl_xor(fns, off); fnc += __shfl_xor(fnc, off);
        }
        __syncthreads();   // red[] reuse
        if (lane == 0) { red[0][wave] = c;   red[1][wave] = fps;
                         red[2][wave] = fpc; red[3][wave] = fns;
                         red[4][wave] = fnc; }
        __syncthreads();
        if (t == 0) {
            float C = 0.f, PS = 0.f, PC = 0.f, NS = 0.f, NC = 0.f;
#pragma unroll
            for (int w = 0; w < 4; ++w) {
                C += red[0][w]; PS += red[1][w]; PC += red[2][w];
                NS += red[3][w]; NC += red[4][w];
            }
            out[0] = C / (float)B_ + PS / fmaxf(PC, 1.f) + NS / fmaxf(NC, 1.f);
        }
    }
}

extern "C" void kernel_launch(void* const* d_in, const int* in_sizes, int n_in,
                              void* d_out, int out_size, void* d_ws, size_t ws_size,
                              hipStream_t stream)
{
    const float* x    = (const float*)d_in[0];
    const int*   lb   = (const int*)d_in[1];
    const float* mem  = (const float*)d_in[2];
    const float* fc_w = (const float*)d_in[3];
    const float* fc_b = (const float*)d_in[4];
    const float* p1w  = (const float*)d_in[5];
    const float* p1b  = (const float*)d_in[6];
    const float* p2w  = (const float*)d_in[7];
    const float* p2b  = (const float*)d_in[8];

    float* ws       = (float*)d_ws;
    ushort* mh      = (ushort*)(ws + OFF_MH);
    ushort* xh      = (ushort*)(ws + OFF_XH);
    float* partials = ws + OFF_PARTIAL;
    ushort* uhf     = (ushort*)(ws + OFF_UHF);
    float* sqn      = ws + OFF_SQN;
    float* clsbuf   = ws + OFF_CLS;
    float* pairpart = ws + OFF_PAIR;
    int*   ctr      = (int*)(ws + OFF_CTR);
    ushort* xbf     = (ushort*)(ws + OFF_XBF);
    ushort* membf   = (ushort*)(ws + OFF_MEMBF);
    ushort* wbf     = (ushort*)(ws + OFF_WBF);
    ushort* p2h     = (ushort*)(ws + OFF_P2H);
    ushort* p1h     = (ushort*)(ws + OFF_P1H);

    // K0: dtype conversions + ctr zero
    prep_cvt<<<(TOT4 + 255) / 256, 256, 0, stream>>>(x, mem, fc_w, p2w, p1w,
                                                     xbf, membf, wbf, p2h, p1h,
                                                     ctr);
    // K1: merged gemms (bf16 in, 64x64 tiles, ~2 blocks/CU) -> f16 xh, mh
    gemm_all<<<456, 256, 0, stream>>>(xbf, membf, wbf, fc_b, xh, mh);
    // K2: fused elementwise logits partials (f16 dot2) + MFMA f16 u-partials
    fused_tile<<<dim3(8, 4, ECHUNKS), 256, 0, stream>>>(xh, mh, p1h, p2h,
                                                        partials);
    // K3: reduce partials + bias, normalize u (f16), classification loss
    reduce_row<<<B_, 256, 0, stream>>>(partials, p1b, p2b, lb, uhf, sqn, clsbuf);
    // K4: pairwise margin losses + last-block finalize
    pair_loss<<<256, 256, 0, stream>>>(uhf, sqn, lb, clsbuf, pairpart, ctr,
                                       (float*)d_out);
}